// Round 6
// baseline (470.439 us; speedup 1.0000x reference)
//
#include <hip/hip_runtime.h>
#include <hip/hip_bf16.h>
#include <math.h>

#define SEQ    2048
#define BATCH  8
#define DMODEL 512
#define NHEADS 8
#define DK     64
#define DFF    2048
#define MROWS  16384

typedef __hip_bfloat16 bf16;
typedef unsigned int   u32;
typedef unsigned short u16;
typedef __attribute__((ext_vector_type(8))) short short8;   // 8 bf16 = 4 VGPR
typedef __attribute__((ext_vector_type(4))) float f32x4;

#define LOG2E  1.4426950408889634f
#define LOG2E2 2.8853900817779268f   // 2*log2(e)
#define MC2    1.4426950408889634f   // log2(e) : +1.0-mask in exp2 domain

__device__ __forceinline__ float b2f(bf16 v) { return __bfloat162float(v); }
__device__ __forceinline__ bf16  f2b(float f) { return __float2bfloat16(f); }
__device__ __forceinline__ u16 f2u(float f) { bf16 h = __float2bfloat16(f); return *(u16*)&h; }
__device__ __forceinline__ u32 pack2(float a, float b) {
    return ((u32)f2u(b) << 16) | (u32)f2u(a);
}
__device__ __forceinline__ void unpack2(u32 u, float& a, float& b) {
    a = __uint_as_float(u << 16);
    b = __uint_as_float(u & 0xFFFF0000u);
}
// external-tensor load: dtype decided at runtime by probe flag (0=bf16, 1=fp32)
__device__ __forceinline__ float ldE(const void* p, long off, int f32) {
    return f32 ? ((const float*)p)[off] : b2f(((const bf16*)p)[off]);
}
// async global->LDS, 16B per lane; lds base must be wave-uniform
__device__ __forceinline__ void async16(bf16* lds, const bf16* g) {
    __builtin_amdgcn_global_load_lds(
        (const __attribute__((address_space(1))) void*)g,
        (__attribute__((address_space(3))) void*)lds, 16, 0, 0);
}

// ---------------------------------------------------------------------------
// Dtype probe (verified round 2): flag=1 means fp32 inputs.
// ---------------------------------------------------------------------------
__global__ __launch_bounds__(256) void probe_kernel(const void* __restrict__ x,
                                                    int* __restrict__ flag)
{
    int tid = threadIdx.x;
    const u16* u = (const u16*)x;
    int cnt = 0;
    #pragma unroll
    for (int i = 0; i < 8; i++) {
        u16 e = u[tid * 8 + i];
        float v = __uint_as_float(((u32)e) << 16);
        float a = fabsf(v);
        if (a > 9.313226e-10f && a < 1.0737418e9f) cnt++;
    }
    __shared__ int sh[256];
    sh[tid] = cnt;
    __syncthreads();
    for (int s = 128; s > 0; s >>= 1) {
        if (tid < s) sh[tid] += sh[tid + s];
        __syncthreads();
    }
    if (tid == 0) *flag = (sh[0] < 1700) ? 1 : 0;
}

// ---------------------------------------------------------------------------
// Merged prep: blocks 0..4095 convert x; blocks 4096.. pack weights.
// Wq,bq pre-scaled by log2e (softmax scale folded into Q).
// ---------------------------------------------------------------------------
__global__ __launch_bounds__(256) void prep_all(
    const void* x, bf16* __restrict__ xb,
    const void* Wq, const void* Wv, const void* Wr, const void* Wo,
    const void* Wf1, const void* Wf2,
    const void* bq, const void* bv, const void* br, const void* bo,
    const void* bf1, const void* bf2,
    bf16* __restrict__ Wqvr, bf16* __restrict__ Wob,
    bf16* __restrict__ Wf1t, bf16* __restrict__ Wf2t,
    bf16* __restrict__ bqvr, bf16* __restrict__ bob,
    bf16* __restrict__ bf1b, bf16* __restrict__ bf2b,
    const int* __restrict__ flagp)
{
    const int f32 = *flagp;
    int bid = blockIdx.x;
    if (bid < 4096) {
        int gid = bid * 256 + threadIdx.x;             // 0..1048575
        int row_in = gid >> 6;                         // s*8+b
        int d8 = (gid & 63) * 8;
        int s = row_in >> 3, b = row_in & 7;
        long src = (long)row_in * 512 + d8;
        long dst = ((long)b * SEQ + s) * 512 + d8;
        if (f32) {
            const float* xf = (const float*)x;
            float4 a = *(const float4*)(xf + src);
            float4 c = *(const float4*)(xf + src + 4);
            u32 o[4] = { pack2(a.x,a.y), pack2(a.z,a.w), pack2(c.x,c.y), pack2(c.z,c.w) };
            *(uint4*)(xb + dst) = *(uint4*)o;
        } else {
            *(uint4*)(xb + dst) = *(const uint4*)((const bf16*)x + src);
        }
        return;
    }
    long g = (long)(bid - 4096) * 256 + threadIdx.x;   // < 3150336
    if (g < 786432) {
        if (g < 262144) Wqvr[g] = f2b(ldE(Wq, g, f32) * LOG2E);   // Q scaled
        else if (g < 524288) Wqvr[g] = f2b(ldE(Wv, g & 262143, f32));
        else Wqvr[g] = f2b(ldE(Wr, g & 262143, f32));
    } else if (g < 1048576) {
        long j = g - 786432;
        Wob[j] = f2b(ldE(Wo, j, f32));
    } else if (g < 2097152) {
        long j = g - 1048576;
        long n = j >> 9, k = j & 511;
        Wf1t[j] = f2b(ldE(Wf1, k * 2048 + n, f32));
    } else if (g < 3145728) {
        long j = g - 2097152;
        long n = j >> 11, k = j & 2047;
        Wf2t[j] = f2b(ldE(Wf2, k * 512 + n, f32));
    } else {
        long j = g - 3145728;
        if (j < 512)       bqvr[j]      = f2b(ldE(bq, j, f32) * LOG2E);
        else if (j < 1024) bqvr[j]      = f2b(ldE(bv, j - 512, f32));
        else if (j < 1536) bqvr[j]      = f2b(ldE(br, j - 1024, f32));
        else if (j < 2048) bob[j-1536]  = f2b(ldE(bo, j - 1536, f32));
        else if (j < 4096) bf1b[j-2048] = f2b(ldE(bf1, j - 2048, f32));
        else if (j < 4608) bf2b[j-4096] = f2b(ldE(bf2, j - 4096, f32));
    }
}

// ---------------------------------------------------------------------------
// MFMA GEMM body, BK=64 as two 32-K panels (verified round 7 / round-2 bench;
// BK=32 dbuf prefetch REGRESSED (round 3): compute phase too short to hide
// load latency and doubled drain points. Keep this form.
// ---------------------------------------------------------------------------
template<bool RELU>
__device__ __forceinline__ void gemm_body(
    const bf16* __restrict__ A, const bf16* __restrict__ W,
    const bf16* __restrict__ bias, bf16* __restrict__ C,
    int K, int lda, int ldc, int bx, int by, bf16* As, bf16* Bs)
{
    const int tid = threadIdx.x;
    const int w = tid >> 6, lane = tid & 63;
    const int li = lane & 15, quad = lane >> 4;
    const int m0 = bx * 128, n0 = by * 128;
    const int wm = (w >> 1) * 64, wn = (w & 1) * 64;
    const int srow = lane >> 2, scol = (lane & 3) * 8;

    f32x4 acc[4][4];
    const f32x4 z4 = {0.f, 0.f, 0.f, 0.f};
    #pragma unroll
    for (int i = 0; i < 4; i++)
        #pragma unroll
        for (int j = 0; j < 4; j++) acc[i][j] = z4;

    const bf16* ga = A + (long)(m0 + w * 32 + srow) * lda + scol;
    const bf16* gb = W + (long)(n0 + w * 32 + srow) * K + scol;
    bf16* lA0 = &As[(w * 32) * 32];
    bf16* lA1 = &As[(w * 32 + 16) * 32];
    bf16* lB0 = &Bs[(w * 32) * 32];
    bf16* lB1 = &Bs[(w * 32 + 16) * 32];

    for (int k0 = 0; k0 < K; k0 += 64) {
        __syncthreads();
        async16(lA0, ga);
        async16(lA1, ga + (long)16 * lda);
        async16(lA0 + 4096, ga + 32);
        async16(lA1 + 4096, ga + 32 + (long)16 * lda);
        async16(lB0, gb);
        async16(lB1, gb + (long)16 * K);
        async16(lB0 + 4096, gb + 32);
        async16(lB1 + 4096, gb + 32 + (long)16 * K);
        ga += 64; gb += 64;
        __syncthreads();
        #pragma unroll
        for (int ks = 0; ks < 2; ks++) {
            short8 af[4], bfr[4];
            #pragma unroll
            for (int t = 0; t < 4; t++)
                af[t] = *(const short8*)&As[ks * 4096 + (wm + t * 16 + li) * 32 + quad * 8];
            #pragma unroll
            for (int t = 0; t < 4; t++)
                bfr[t] = *(const short8*)&Bs[ks * 4096 + (wn + t * 16 + li) * 32 + quad * 8];
            #pragma unroll
            for (int i = 0; i < 4; i++)
                #pragma unroll
                for (int j = 0; j < 4; j++)
                    acc[i][j] = __builtin_amdgcn_mfma_f32_16x16x32_bf16(
                        af[i], bfr[j], acc[i][j], 0, 0, 0);
        }
    }

    #pragma unroll
    for (int i = 0; i < 4; i++) {
        #pragma unroll
        for (int j = 0; j < 4; j++) {
            int col = n0 + wn + j * 16 + li;
            float bb = b2f(bias[col]);
            #pragma unroll
            for (int r = 0; r < 4; r++) {
                int row = m0 + wm + i * 16 + quad * 4 + r;
                float v = acc[i][j][r] + bb;
                if (RELU) v = fmaxf(v, 0.f);
                C[(long)row * ldc + col] = f2b(v);
            }
        }
    }
}

template<bool RELU>
__global__ __launch_bounds__(256) void mfma_gemm(
    const bf16* __restrict__ A, const bf16* __restrict__ W,
    const bf16* __restrict__ bias, bf16* __restrict__ C,
    int K, int lda, int ldc)
{
    __shared__ bf16 As[8192];
    __shared__ bf16 Bs[8192];
    gemm_body<RELU>(A, W, bias, C, K, lda, ldc, blockIdx.x, blockIdx.y, As, Bs);
}

// ---------------------------------------------------------------------------
// Parallel chunked recurrence (round-10, verified). Contracting tanh map:
// 64-step warm-up from h=0 reconstructs state below bf16 noise. Serial depth
// 2048 -> 192, threads 4096 -> 65536. Reads R (cols 1024..1535), writes
// H*0.125 into the V slots (cols 512..1023, dead after vt_kernel).
// ---------------------------------------------------------------------------
__global__ __launch_bounds__(256) void recur_par(bf16* __restrict__ QVR,
                                                 const void* __restrict__ Wh,
                                                 const int* __restrict__ flagp)
{
    const int f32 = *flagp;
    const int idx = blockIdx.x * 256 + threadIdx.x;   // 0..65535
    const int k   = idx >> 12;                        // chunk 0..15
    const int rem = idx & 4095;
    const int b   = rem >> 9, o = rem & 511;

    float w = 0.0f;
    #pragma unroll
    for (int j = 0; j < DK; j++) w += ldE(Wh, (long)o * DK + j, f32);
    const float w2 = w * LOG2E2;

    const bf16* rb = QVR + (long)b * SEQ * 1536 + 1024 + o;   // R source
    bf16*       hb = QVR + (long)b * SEQ * 1536 + 512  + o;   // H dest (V slots)

    const int s1   = k * 128;                  // first stored step
    const int s0   = (k == 0) ? 0 : s1 - 64;   // warm-up start
    const int warm = s1 - s0;                  // 0 or 64 (multiple of PF)
    const int TOT  = 128 + warm;               // 128 or 192

    const int PF = 32;
    float buf[PF];
    #pragma unroll
    for (int i = 0; i < PF; i++)
        buf[i] = b2f(rb[(long)(s0 + i) * 1536]) * LOG2E2;

    float h = 0.0f;
    for (int t = 0; t < TOT; t += PF) {
        float nbuf[PF];
        if (t + PF < TOT) {
            #pragma unroll
            for (int i = 0; i < PF; i++)
                nbuf[i] = b2f(rb[(long)(s0 + t + PF + i) * 1536]) * LOG2E2;
        }
        const bool store = (t >= warm);        // block-uniform
        #pragma unroll
        for (int i = 0; i < PF; i++) {
            float xx = fmaf(h, w2, buf[i]);            // 2*log2e*(h*w + r)
            float e  = __builtin_amdgcn_exp2f(xx);
            float d  = __builtin_amdgcn_rcpf(e + 1.0f);
            h = fmaf(-2.0f, d, 1.0f);                  // tanh
            if (store) hb[(long)(s0 + t + i) * 1536] = f2b(h * 0.125f);
        }
        #pragma unroll
        for (int i = 0; i < PF; i++) buf[i] = nbuf[i];
    }
}

// ---------------------------------------------------------------------------
// V^T precompute with pre-applied XOR swizzle (verified round 7/round-2).
// Swizzle permutes 8-key groups WITHIN each 32-key half (sg&4 preserved).
// ---------------------------------------------------------------------------
__global__ __launch_bounds__(256) void vt_kernel(const bf16* __restrict__ QVR,
                                                 bf16* __restrict__ VTg)
{
    __shared__ bf16 Ls[64 * 72];   // [s][d], pad 8
    int bh = blockIdx.y, b = bh >> 3, h = bh & 7;
    int s0 = blockIdx.x * 64;
    int t = threadIdx.x;
    #pragma unroll
    for (int i = 0; i < 2; i++) {
        int item = t + i * 256;
        int s = item >> 3, d8 = (item & 7) * 8;
        uint4 v = *(const uint4*)&QVR[((long)(b * SEQ + s0 + s)) * 1536 + 512 + h * 64 + d8];
        *(uint2*)&Ls[s * 72 + d8]     = make_uint2(v.x, v.y);
        *(uint2*)&Ls[s * 72 + d8 + 4] = make_uint2(v.z, v.w);
    }
    __syncthreads();
    #pragma unroll
    for (int i = 0; i < 2; i++) {
        int item = t + i * 256;
        int d = item >> 3, sg = item & 7;
        bf16 tmp[8];
        #pragma unroll
        for (int j = 0; j < 8; j++) tmp[j] = Ls[(sg * 8 + j) * 72 + d];
        int sgp = (sg & 4) | ((sg & 3) ^ ((d >> 3) & 3));
        *(uint4*)&VTg[((long)bh * 64 + d) * 2048 + s0 + sgp * 8] = *(uint4*)tmp;
    }
}

// ---------------------------------------------------------------------------
// MFMA flash attention, round-14 = round-13 (verified: 64-key windows,
// dbuf K/V, prefetch-before-compute, 32-key halves, LDS 53248) + Kt
// XOR-swizzle. Old Kt [key][32d] row stride = 64B = 16 banks -> even/odd li
// lanes collided ~4-way on every K ds_read_b128 (the measured 1.05e7
// SQ_LDS_BANK_CONFLICT). Fix per rule #21 (both-sides-or-neither): the
// global SOURCE column is pre-swizzled (slot ^= (key>>1)&3, g = (lane>>3)&3
// at staging since key%16 = lane>>2), LDS dest stays linear (global_load_lds
// requirement), and the read XORs the same term: Kt[key][quad^g] =
// K[key][quad] exactly. New read bank = 16(li&1)+4(quad^((li>>1)&3)):
// 2 lanes/bank = free (m136). Arithmetic bit-identical.
// ---------------------------------------------------------------------------
__global__ __launch_bounds__(512) void attn_mfma(const bf16* __restrict__ QVR,
                                                 const bf16* __restrict__ VTg,
                                                 bf16* __restrict__ O)
{
    __shared__ bf16 Kt[2][4096];          // [buf][ksd*2048 + key*32 + d^swz]
    __shared__ bf16 Vt[2][4096];          // [buf][half*2048 + d*32 + key'], swizzled
    __shared__ bf16 Pl[8 * 32 * 40];      // per-wave P [qrow][32key], pad 40
    const int tid = threadIdx.x;
    const int w = tid >> 6, lane = tid & 63;
    const int li = lane & 15, quad = lane >> 4;
    const int bh = blockIdx.y;
    const int b = bh >> 3, hd = bh & 7;
    const int q0 = blockIdx.x * 256;
    const int qw = q0 + w * 32;                    // wave's q base
    const long rowb = (long)b * SEQ;
    const bf16* Qb = QVR + hd * DK;
    const bf16* Hb = QVR + 512 + hd * DK;          // H in V slots
    bf16* Pw = &Pl[w * 32 * 40];
    const f32x4 z4 = {0.f, 0.f, 0.f, 0.f};

    short8 ones;
    #pragma unroll
    for (int i = 0; i < 8; i++) ones[i] = (short)0x3F80;   // bf16 1.0

    // Q as A-operand fragments (verified mapping)
    short8 qa[2][2];
    #pragma unroll
    for (int mt = 0; mt < 2; mt++)
        #pragma unroll
        for (int ks = 0; ks < 2; ks++)
            qa[mt][ks] = *(const short8*)&Qb[(rowb + qw + mt * 16 + li) * 1536
                                             + ks * 32 + quad * 8];

    f32x4 oacc[2][4];
    f32x4 lacc[2];
    #pragma unroll
    for (int mt = 0; mt < 2; mt++) {
        #pragma unroll
        for (int dt = 0; dt < 4; dt++) oacc[mt][dt] = z4;
        lacc[mt] = z4;
    }

    // per-wave staging source pointers (wave 0..3: K/H rows; wave 4..7: V^T)
    // K source col pre-swizzled: slot (lane&3) ^ g, g = (lane>>3)&3
    const bf16* gk = Hb + (rowb + w * 16 + (lane >> 2)) * 1536
                     + (((lane & 3) ^ ((lane >> 3) & 3)) * 8);
    const bf16* gv = VTg + ((long)bh * 64 + (w - 4) * 16 + (lane >> 2)) * 2048
                     + (lane & 3) * 8;
    const int gkr = (li >> 1) & 3;                 // read-side XOR term

    // prologue: stage window 0 into buffer 0
    if (w < 4) {
        async16(&Kt[0][w * 512],        gk);
        async16(&Kt[0][2048 + w * 512], gk + 32);
    } else {
        async16(&Vt[0][(w - 4) * 512],        gv);
        async16(&Vt[0][2048 + (w - 4) * 512], gv + 32);
    }
    gk += (long)64 * 1536;
    gv += 64;
    __syncthreads();

    for (int t = 0; t < 32; t++) {
        const int cb = t & 1, nb = cb ^ 1;

        // ---- prefetch window t+1 into the other buffer (issue-only) ----
        if (t < 31) {
            if (w < 4) {
                async16(&Kt[nb][w * 512],        gk);
                async16(&Kt[nb][2048 + w * 512], gk + 32);
            } else {
                async16(&Vt[nb][(w - 4) * 512],        gv);
                async16(&Vt[nb][2048 + (w - 4) * 512], gv + 32);
            }
            gk += (long)64 * 1536;
            gv += 64;
        }

        const int kt2 = t * 64;
        const bf16* Kp = Kt[cb];
        const bf16* Vp = Vt[cb];

        // ---- two 32-key halves per window (P buffer is half-width) ----
        #pragma unroll
        for (int half = 0; half < 2; half++) {
            const int kt2h = kt2 + half * 32;

            // S = Q K^T for this half's 2 key tiles (full 64-d)
            f32x4 sa[2][2];
            #pragma unroll
            for (int mt = 0; mt < 2; mt++)
                #pragma unroll
                for (int nt = 0; nt < 2; nt++) sa[mt][nt] = z4;
            #pragma unroll
            for (int ksd = 0; ksd < 2; ksd++) {
                short8 kb[2];
                #pragma unroll
                for (int nt = 0; nt < 2; nt++)
                    kb[nt] = *(const short8*)&Kp[ksd * 2048
                               + ((half * 2 + nt) * 16 + li) * 32
                               + ((quad ^ gkr) * 8)];
                #pragma unroll
                for (int mt = 0; mt < 2; mt++)
                    #pragma unroll
                    for (int nt = 0; nt < 2; nt++)
                        sa[mt][nt] = __builtin_amdgcn_mfma_f32_16x16x32_bf16(
                            qa[mt][ksd], kb[nt], sa[mt][nt], 0, 0, 0);
            }

            // p = exp2(s [+ log2e]); write P (32 cols)
            bool nomask  = (kt2h + 31 <= qw);      // max key <= min q
            bool allmask = (kt2h > qw + 31);       // min key > max q
            if (nomask || allmask) {
                float MB = allmask ? MC2 : 0.0f;
                #pragma unroll
                for (int mt = 0; mt < 2; mt++)
                    #pragma unroll
                    for (int nt = 0; nt < 2; nt++) {
                        f32x4 s = sa[mt][nt];
                        #pragma unroll
                        for (int r = 0; r < 4; r++) {
                            float p = __builtin_amdgcn_exp2f(s[r] + MB);
                            Pw[(mt * 16 + quad * 4 + r) * 40 + nt * 16 + li] = f2b(p);
                        }
                    }
            } else {
                #pragma unroll
                for (int mt = 0; mt < 2; mt++) {
                    int qrow = qw + mt * 16 + quad * 4;     // + r below
                    #pragma unroll
                    for (int nt = 0; nt < 2; nt++) {
                        int key = kt2h + nt * 16 + li;
                        f32x4 s = sa[mt][nt];
                        #pragma unroll
                        for (int r = 0; r < 4; r++) {
                            float arg = (key > qrow + r) ? s[r] + MC2 : s[r];
                            float p = __builtin_amdgcn_exp2f(arg);
                            Pw[(mt * 16 + quad * 4 + r) * 40 + nt * 16 + li] = f2b(p);
                        }
                    }
                }
            }

            // O += P V ;  l += P 1 (matrix pipe), keys of this half
            short8 vbf[4], pa[2];
            #pragma unroll
            for (int dt = 0; dt < 4; dt++) {
                int d = dt * 16 + li;
                int sw = ((d >> 3) & 3) << 3;
                vbf[dt] = *(const short8*)&Vp[half * 2048 + d * 32 + ((quad * 8) ^ sw)];
            }
            #pragma unroll
            for (int mt = 0; mt < 2; mt++)
                pa[mt] = *(const short8*)&Pw[(mt * 16 + li) * 40 + quad * 8];
            #pragma unroll
            for (int mt = 0; mt < 2; mt++) {
                lacc[mt] = __builtin_amdgcn_mfma_f32_16x16x32_bf16(
                    pa[mt], ones, lacc[mt], 0, 0, 0);
                #pragma unroll
                for (int dt = 0; dt < 4; dt++)
                    oacc[mt][dt] = __builtin_amdgcn_mfma_f32_16x16x32_bf16(
                        pa[mt], vbf[dt], oacc[mt][dt], 0, 0, 0);
            }
        }

        // one barrier per window: vmcnt(0)+lgkmcnt(0) drain covers the
        // prefetch (which had the whole compute above to complete) and
        // orders the buffer swap (WAR on Kt/Vt[nb] next iteration).
        __syncthreads();
    }

    #pragma unroll
    for (int mt = 0; mt < 2; mt++)
        #pragma unroll
        for (int r = 0; r < 4; r++) {
            float inv = 1.0f / lacc[mt][r];
            long row = rowb + qw + mt * 16 + quad * 4 + r;
            #pragma unroll
            for (int dt = 0; dt < 4; dt++)
                O[row * 512 + hd * 64 + dt * 16 + li] = f2b(oacc[mt][dt][r] * inv);
        }
}

// ---------------------------------------------------------------------------
// LN1 round-14: wave-per-row (64 lanes x 8 bf16 = 16B/lane loads, G13),
// shfl-xor butterfly reduce only — no LDS, no barrier. 4 rows per block.
// xb + AO (both bf16 plain) -> X1 bf16 plain.
// ---------------------------------------------------------------------------
__global__ __launch_bounds__(256) void ln1_kernel(const bf16* __restrict__ xb,
                                                  const bf16* __restrict__ ao,
                                                  const void* __restrict__ g,
                                                  const void* __restrict__ beta,
                                                  bf16* __restrict__ x1,
                                                  const int* __restrict__ flagp)
{
    const int f32 = *flagp;
    const int w = threadIdx.x >> 6, lane = threadIdx.x & 63;
    const long m = (long)blockIdx.x * 4 + w;
    const long base = m * 512;
    const int d0 = lane * 8;

    uint4 xv = *(const uint4*)&xb[base + d0];
    uint4 av = *(const uint4*)&ao[base + d0];
    u32 xs[4] = { xv.x, xv.y, xv.z, xv.w };
    u32 as[4] = { av.x, av.y, av.z, av.w };
    float v[8];
    float s1 = 0.f, s2 = 0.f;
    #pragma unroll
    for (int i = 0; i < 4; i++) {
        float a0, a1, c0, c1;
        unpack2(xs[i], a0, a1);
        unpack2(as[i], c0, c1);
        v[2*i]   = a0 + c0;
        v[2*i+1] = a1 + c1;
        s1 += v[2*i] + v[2*i+1];
        s2 += v[2*i]*v[2*i] + v[2*i+1]*v[2*i+1];
    }
    #pragma unroll
    for (int off = 32; off > 0; off >>= 1) {
        s1 += __shfl_xor(s1, off);
        s2 += __shfl_xor(s2, off);
    }
    float mu = s1 * (1.0f / DMODEL);
    float var = s2 * (1.0f / DMODEL) - mu * mu;
    float rs = rsqrtf(var + 1e-5f);
    u32 o[4];
    #pragma unroll
    for (int i = 0; i < 4; i++) {
        float r0 = (v[2*i]   - mu) * rs * ldE(g, d0 + 2*i,     f32) + ldE(beta, d0 + 2*i,     f32);
        float r1 = (v[2*i+1] - mu) * rs * ldE(g, d0 + 2*i + 1, f32) + ldE(beta, d0 + 2*i + 1, f32);
        o[i] = pack2(r0, r1);
    }
    *(uint4*)&x1[base + d0] = *(uint4*)o;
}

// ---------------------------------------------------------------------------
// LN2 round-14: wave-per-row like LN1. X1 + FF2 -> d_out (external dtype,
// (S,B,D) layout).
// ---------------------------------------------------------------------------
__global__ __launch_bounds__(256) void ln2_kernel(const bf16* __restrict__ x1,
                                                  const bf16* __restrict__ ff2,
                                                  const void* __restrict__ g,
                                                  const void* __restrict__ beta,
                                                  void* __restrict__ outp,
                                                  const int* __restrict__ flagp)
{
    const int f32 = *flagp;
    const int w = threadIdx.x >> 6, lane = threadIdx.x & 63;
    const int m = blockIdx.x * 4 + w;          // b*SEQ + s
    const int b = m >> 11, s = m & 2047;
    const long plain = (long)m * 512;
    const long funny = ((long)s * BATCH + b) * 512;
    const int d0 = lane * 8;

    uint4 xv = *(const uint4*)&x1[plain + d0];
    uint4 av = *(const uint4*)&ff2[plain + d0];
    u32 xs[4] = { xv.x, xv.y, xv.z, xv.w };
    u32 as[4] = { av.x, av.y, av.z, av.w };
    float v[8];
    float s1 = 0.f, s2 = 0.f;
    #pragma unroll
    for (int i = 0; i < 4; i++) {
        float a0, a1, c0, c1;
        unpack2(xs[i], a0, a1);
        unpack2(as[i], c0, c1);
        v[2*i]   = a0 + c0;
        v[2*i+1] = a1 + c1;
        s1 += v[2*i] + v[2*i+1];
        s2 += v[2*i]*v[2*i] + v[2*i+1]*v[2*i+1];
    }
    #pragma unroll
    for (int off = 32; off > 0; off >>= 1) {
        s1 += __shfl_xor(s1, off);
        s2 += __shfl_xor(s2, off);
    }
    float mu = s1 * (1.0f / DMODEL);
    float var = s2 * (1.0f / DMODEL) - mu * mu;
    float rs = rsqrtf(var + 1e-5f);
    float r[8];
    #pragma unroll
    for (int i = 0; i < 8; i++)
        r[i] = (v[i] - mu) * rs * ldE(g, d0 + i, f32) + ldE(beta, d0 + i, f32);
    if (f32) {
        float* op = (float*)outp + funny + d0;
        float4 f0 = { r[0], r[1], r[2], r[3] };
        float4 f1 = { r[4], r[5], r[6], r[7] };
        *(float4*)(op)     = f0;
        *(float4*)(op + 4) = f1;
    } else {
        u32 o[4];
        #pragma unroll
        for (int i = 0; i < 4; i++) o[i] = pack2(r[2*i], r[2*i+1]);
        *(uint4*)&((bf16*)outp)[funny + d0] = *(uint4*)o;
    }
}

// ---------------------------------------------------------------------------
extern "C" void kernel_launch(void* const* d_in, const int* in_sizes, int n_in,
                              void* d_out, int out_size, void* d_ws, size_t ws_size,
                              hipStream_t stream)
{
    (void)in_sizes; (void)n_in; (void)out_size; (void)ws_size;
    const void* x = d_in[0];

    // bf16 workspace layout (elements):
    bf16* W    = (bf16*)d_ws;
    bf16* xb   = W;                       // [0, 8M)   dead after LN1
    bf16* QVR  = W + (8u  << 20);         // [8M, 32M) Q|V|R cols; H written into V slots
    bf16* Ob   = W + (32u << 20);         // [32M,40M) dead after Wo gemm
    bf16* VTg  = W + (40u << 20);         // [40M,48M) V^T swizzled, dead after attn
    bf16* AO   = W + (40u << 20);         // same region, written after attn
    bf16* X1   = W + (8u  << 20);         // reuse QVR head, alive until LN2
    bf16* FFH  = W + (16u << 20);         // [16M,48M) after LN1
    bf16* FF2  = W;                       // reuse xb
    int*  flag = (int*)((char*)d_ws + (size_t)96 * 1024 * 1024);
    bf16* Wt   = (bf16*)((char*)d_ws + (size_t)96 * 1024 * 1024 + 16);
    bf16* Wqvr = Wt;                      // [1536][512]
    bf16* Wob  = Wt + 786432;             // [512][512]
    bf16* Wf1t = Wt + 1048576;            // [2048][512]
    bf16* Wf2t = Wt + 2097152;            // [512][2048]
    bf16* bqvr = Wt + 3145728;
    bf16* bob  = Wt + 3147264;
    bf16* bf1b = Wt + 3147776;
    bf16* bf2b = Wt + 3149824;

    dim3 blk(256);
    probe_kernel<<<1, blk, 0, stream>>>(x, flag);
    prep_all<<<16402, blk, 0, stream>>>(
        x, xb,
        d_in[1], d_in[3], d_in[5], d_in[8], d_in[12], d_in[14],
        d_in[2], d_in[4], d_in[6], d_in[9], d_in[13], d_in[15],
        Wqvr, Wob, Wf1t, Wf2t, bqvr, bob, bf1b, bf2b, flag);

    // combined Q|V|R projection: all 1536 output columns in one dispatch
    mfma_gemm<false><<<dim3(128, 12), blk, 0, stream>>>(
        xb, Wqvr, bqvr, QVR, 512, 512, 1536);

    // V^T precompute (swizzled) into VTg — consumes V slots before recur
    vt_kernel<<<dim3(32, 64), blk, 0, stream>>>(QVR, VTg);

    // chunk-parallel recurrence: R (cols 1024..1535) -> H (cols 512..1023)
    recur_par<<<256, blk, 0, stream>>>(QVR, d_in[7], flag);

    // attention: 512-thread blocks, 256 q-rows each, 64-key prefetched windows
    attn_mfma<<<dim3(8, 64), dim3(512), 0, stream>>>(QVR, VTg, Ob);

    // Wo projection
    mfma_gemm<false><<<dim3(128, 4), blk, 0, stream>>>(Ob, Wob, bob, AO, 512, 512, 512);

    // LN1 (wave-per-row, 4 rows/block)
    ln1_kernel<<<MROWS / 4, blk, 0, stream>>>(xb, AO, d_in[10], d_in[11], X1, flag);

    // FF1 (relu)
    mfma_gemm<true><<<dim3(128, 16), blk, 0, stream>>>(X1, Wf1t, bf1b, FFH, 512, 512, 2048);

    // FF2
    mfma_gemm<false><<<dim3(128, 4), blk, 0, stream>>>(FFH, Wf2t, bf2b, FF2, 2048, 2048, 512);

    // LN2 -> d_out (wave-per-row, 4 rows/block)
    ln2_kernel<<<MROWS / 4, blk, 0, stream>>>(X1, FF2, d_in[16], d_in[17], d_out, flag);
}

// Round 7
// 428.335 us; speedup vs baseline: 1.0983x; 1.0983x over previous
//
#include <hip/hip_runtime.h>
#include <hip/hip_bf16.h>
#include <math.h>

#define SEQ    2048
#define BATCH  8
#define DMODEL 512
#define NHEADS 8
#define DK     64
#define DFF    2048
#define MROWS  16384

typedef __hip_bfloat16 bf16;
typedef unsigned int   u32;
typedef unsigned short u16;
typedef __attribute__((ext_vector_type(8))) short short8;   // 8 bf16 = 4 VGPR
typedef __attribute__((ext_vector_type(4))) float f32x4;

#define LOG2E  1.4426950408889634f
#define LOG2E2 2.8853900817779268f   // 2*log2(e)
#define MC2    1.4426950408889634f   // log2(e) : +1.0-mask in exp2 domain

__device__ __forceinline__ float b2f(bf16 v) { return __bfloat162float(v); }
__device__ __forceinline__ bf16  f2b(float f) { return __float2bfloat16(f); }
__device__ __forceinline__ u16 f2u(float f) { bf16 h = __float2bfloat16(f); return *(u16*)&h; }
__device__ __forceinline__ u32 pack2(float a, float b) {
    return ((u32)f2u(b) << 16) | (u32)f2u(a);
}
__device__ __forceinline__ void unpack2(u32 u, float& a, float& b) {
    a = __uint_as_float(u << 16);
    b = __uint_as_float(u & 0xFFFF0000u);
}
// external-tensor load: dtype decided at runtime by probe flag (0=bf16, 1=fp32)
__device__ __forceinline__ float ldE(const void* p, long off, int f32) {
    return f32 ? ((const float*)p)[off] : b2f(((const bf16*)p)[off]);
}
// async global->LDS, 16B per lane; lds base must be wave-uniform
__device__ __forceinline__ void async16(bf16* lds, const bf16* g) {
    __builtin_amdgcn_global_load_lds(
        (const __attribute__((address_space(1))) void*)g,
        (__attribute__((address_space(3))) void*)lds, 16, 0, 0);
}

// ---------------------------------------------------------------------------
// Dtype probe (verified round 2): flag=1 means fp32 inputs.
// ---------------------------------------------------------------------------
__global__ __launch_bounds__(256) void probe_kernel(const void* __restrict__ x,
                                                    int* __restrict__ flag)
{
    int tid = threadIdx.x;
    const u16* u = (const u16*)x;
    int cnt = 0;
    #pragma unroll
    for (int i = 0; i < 8; i++) {
        u16 e = u[tid * 8 + i];
        float v = __uint_as_float(((u32)e) << 16);
        float a = fabsf(v);
        if (a > 9.313226e-10f && a < 1.0737418e9f) cnt++;
    }
    __shared__ int sh[256];
    sh[tid] = cnt;
    __syncthreads();
    for (int s = 128; s > 0; s >>= 1) {
        if (tid < s) sh[tid] += sh[tid + s];
        __syncthreads();
    }
    if (tid == 0) *flag = (sh[0] < 1700) ? 1 : 0;
}

// ---------------------------------------------------------------------------
// Merged prep: blocks 0..4095 convert x; blocks 4096.. pack weights.
// Wq,bq pre-scaled by log2e (softmax scale folded into Q).
// ---------------------------------------------------------------------------
__global__ __launch_bounds__(256) void prep_all(
    const void* x, bf16* __restrict__ xb,
    const void* Wq, const void* Wv, const void* Wr, const void* Wo,
    const void* Wf1, const void* Wf2,
    const void* bq, const void* bv, const void* br, const void* bo,
    const void* bf1, const void* bf2,
    bf16* __restrict__ Wqvr, bf16* __restrict__ Wob,
    bf16* __restrict__ Wf1t, bf16* __restrict__ Wf2t,
    bf16* __restrict__ bqvr, bf16* __restrict__ bob,
    bf16* __restrict__ bf1b, bf16* __restrict__ bf2b,
    const int* __restrict__ flagp)
{
    const int f32 = *flagp;
    int bid = blockIdx.x;
    if (bid < 4096) {
        int gid = bid * 256 + threadIdx.x;             // 0..1048575
        int row_in = gid >> 6;                         // s*8+b
        int d8 = (gid & 63) * 8;
        int s = row_in >> 3, b = row_in & 7;
        long src = (long)row_in * 512 + d8;
        long dst = ((long)b * SEQ + s) * 512 + d8;
        if (f32) {
            const float* xf = (const float*)x;
            float4 a = *(const float4*)(xf + src);
            float4 c = *(const float4*)(xf + src + 4);
            u32 o[4] = { pack2(a.x,a.y), pack2(a.z,a.w), pack2(c.x,c.y), pack2(c.z,c.w) };
            *(uint4*)(xb + dst) = *(uint4*)o;
        } else {
            *(uint4*)(xb + dst) = *(const uint4*)((const bf16*)x + src);
        }
        return;
    }
    long g = (long)(bid - 4096) * 256 + threadIdx.x;   // < 3150336
    if (g < 786432) {
        if (g < 262144) Wqvr[g] = f2b(ldE(Wq, g, f32) * LOG2E);   // Q scaled
        else if (g < 524288) Wqvr[g] = f2b(ldE(Wv, g & 262143, f32));
        else Wqvr[g] = f2b(ldE(Wr, g & 262143, f32));
    } else if (g < 1048576) {
        long j = g - 786432;
        Wob[j] = f2b(ldE(Wo, j, f32));
    } else if (g < 2097152) {
        long j = g - 1048576;
        long n = j >> 9, k = j & 511;
        Wf1t[j] = f2b(ldE(Wf1, k * 2048 + n, f32));
    } else if (g < 3145728) {
        long j = g - 2097152;
        long n = j >> 11, k = j & 2047;
        Wf2t[j] = f2b(ldE(Wf2, k * 512 + n, f32));
    } else {
        long j = g - 3145728;
        if (j < 512)       bqvr[j]      = f2b(ldE(bq, j, f32) * LOG2E);
        else if (j < 1024) bqvr[j]      = f2b(ldE(bv, j - 512, f32));
        else if (j < 1536) bqvr[j]      = f2b(ldE(br, j - 1024, f32));
        else if (j < 2048) bob[j-1536]  = f2b(ldE(bo, j - 1536, f32));
        else if (j < 4096) bf1b[j-2048] = f2b(ldE(bf1, j - 2048, f32));
        else if (j < 4608) bf2b[j-4096] = f2b(ldE(bf2, j - 4096, f32));
    }
}

// ---------------------------------------------------------------------------
// MFMA GEMM body, BK=64 as two 32-K panels (verified round 7 / round-2 bench;
// BK=32 dbuf prefetch REGRESSED (round 3). Keep this form.
// ---------------------------------------------------------------------------
template<bool RELU>
__device__ __forceinline__ void gemm_body(
    const bf16* __restrict__ A, const bf16* __restrict__ W,
    const bf16* __restrict__ bias, bf16* __restrict__ C,
    int K, int lda, int ldc, int bx, int by, bf16* As, bf16* Bs)
{
    const int tid = threadIdx.x;
    const int w = tid >> 6, lane = tid & 63;
    const int li = lane & 15, quad = lane >> 4;
    const int m0 = bx * 128, n0 = by * 128;
    const int wm = (w >> 1) * 64, wn = (w & 1) * 64;
    const int srow = lane >> 2, scol = (lane & 3) * 8;

    f32x4 acc[4][4];
    const f32x4 z4 = {0.f, 0.f, 0.f, 0.f};
    #pragma unroll
    for (int i = 0; i < 4; i++)
        #pragma unroll
        for (int j = 0; j < 4; j++) acc[i][j] = z4;

    const bf16* ga = A + (long)(m0 + w * 32 + srow) * lda + scol;
    const bf16* gb = W + (long)(n0 + w * 32 + srow) * K + scol;
    bf16* lA0 = &As[(w * 32) * 32];
    bf16* lA1 = &As[(w * 32 + 16) * 32];
    bf16* lB0 = &Bs[(w * 32) * 32];
    bf16* lB1 = &Bs[(w * 32 + 16) * 32];

    for (int k0 = 0; k0 < K; k0 += 64) {
        __syncthreads();
        async16(lA0, ga);
        async16(lA1, ga + (long)16 * lda);
        async16(lA0 + 4096, ga + 32);
        async16(lA1 + 4096, ga + 32 + (long)16 * lda);
        async16(lB0, gb);
        async16(lB1, gb + (long)16 * K);
        async16(lB0 + 4096, gb + 32);
        async16(lB1 + 4096, gb + 32 + (long)16 * K);
        ga += 64; gb += 64;
        __syncthreads();
        #pragma unroll
        for (int ks = 0; ks < 2; ks++) {
            short8 af[4], bfr[4];
            #pragma unroll
            for (int t = 0; t < 4; t++)
                af[t] = *(const short8*)&As[ks * 4096 + (wm + t * 16 + li) * 32 + quad * 8];
            #pragma unroll
            for (int t = 0; t < 4; t++)
                bfr[t] = *(const short8*)&Bs[ks * 4096 + (wn + t * 16 + li) * 32 + quad * 8];
            #pragma unroll
            for (int i = 0; i < 4; i++)
                #pragma unroll
                for (int j = 0; j < 4; j++)
                    acc[i][j] = __builtin_amdgcn_mfma_f32_16x16x32_bf16(
                        af[i], bfr[j], acc[i][j], 0, 0, 0);
        }
    }

    #pragma unroll
    for (int i = 0; i < 4; i++) {
        #pragma unroll
        for (int j = 0; j < 4; j++) {
            int col = n0 + wn + j * 16 + li;
            float bb = b2f(bias[col]);
            #pragma unroll
            for (int r = 0; r < 4; r++) {
                int row = m0 + wm + i * 16 + quad * 4 + r;
                float v = acc[i][j][r] + bb;
                if (RELU) v = fmaxf(v, 0.f);
                C[(long)row * ldc + col] = f2b(v);
            }
        }
    }
}

template<bool RELU>
__global__ __launch_bounds__(256) void mfma_gemm(
    const bf16* __restrict__ A, const bf16* __restrict__ W,
    const bf16* __restrict__ bias, bf16* __restrict__ C,
    int K, int lda, int ldc)
{
    __shared__ bf16 As[8192];
    __shared__ bf16 Bs[8192];
    gemm_body<RELU>(A, W, bias, C, K, lda, ldc, blockIdx.x, blockIdx.y, As, Bs);
}

// ---------------------------------------------------------------------------
// Parallel chunked recurrence (round-10, verified). Contracting tanh map:
// 64-step warm-up from h=0 reconstructs state below bf16 noise. Serial depth
// 2048 -> 192, threads 4096 -> 65536. Reads R (cols 1024..1535), writes
// H*0.125 into the V slots (cols 512..1023, dead after vt_kernel).
// ---------------------------------------------------------------------------
__global__ __launch_bounds__(256) void recur_par(bf16* __restrict__ QVR,
                                                 const void* __restrict__ Wh,
                                                 const int* __restrict__ flagp)
{
    const int f32 = *flagp;
    const int idx = blockIdx.x * 256 + threadIdx.x;   // 0..65535
    const int k   = idx >> 12;                        // chunk 0..15
    const int rem = idx & 4095;
    const int b   = rem >> 9, o = rem & 511;

    float w = 0.0f;
    #pragma unroll
    for (int j = 0; j < DK; j++) w += ldE(Wh, (long)o * DK + j, f32);
    const float w2 = w * LOG2E2;

    const bf16* rb = QVR + (long)b * SEQ * 1536 + 1024 + o;   // R source
    bf16*       hb = QVR + (long)b * SEQ * 1536 + 512  + o;   // H dest (V slots)

    const int s1   = k * 128;                  // first stored step
    const int s0   = (k == 0) ? 0 : s1 - 64;   // warm-up start
    const int warm = s1 - s0;                  // 0 or 64 (multiple of PF)
    const int TOT  = 128 + warm;               // 128 or 192

    const int PF = 32;
    float buf[PF];
    #pragma unroll
    for (int i = 0; i < PF; i++)
        buf[i] = b2f(rb[(long)(s0 + i) * 1536]) * LOG2E2;

    float h = 0.0f;
    for (int t = 0; t < TOT; t += PF) {
        float nbuf[PF];
        if (t + PF < TOT) {
            #pragma unroll
            for (int i = 0; i < PF; i++)
                nbuf[i] = b2f(rb[(long)(s0 + t + PF + i) * 1536]) * LOG2E2;
        }
        const bool store = (t >= warm);        // block-uniform
        #pragma unroll
        for (int i = 0; i < PF; i++) {
            float xx = fmaf(h, w2, buf[i]);            // 2*log2e*(h*w + r)
            float e  = __builtin_amdgcn_exp2f(xx);
            float d  = __builtin_amdgcn_rcpf(e + 1.0f);
            h = fmaf(-2.0f, d, 1.0f);                  // tanh
            if (store) hb[(long)(s0 + t + i) * 1536] = f2b(h * 0.125f);
        }
        #pragma unroll
        for (int i = 0; i < PF; i++) buf[i] = nbuf[i];
    }
}

// ---------------------------------------------------------------------------
// V^T precompute with pre-applied XOR swizzle (verified round 7/round-2).
// Swizzle permutes 8-key groups WITHIN each 32-key half (sg&4 preserved).
// ---------------------------------------------------------------------------
__global__ __launch_bounds__(256) void vt_kernel(const bf16* __restrict__ QVR,
                                                 bf16* __restrict__ VTg)
{
    __shared__ bf16 Ls[64 * 72];   // [s][d], pad 8
    int bh = blockIdx.y, b = bh >> 3, h = bh & 7;
    int s0 = blockIdx.x * 64;
    int t = threadIdx.x;
    #pragma unroll
    for (int i = 0; i < 2; i++) {
        int item = t + i * 256;
        int s = item >> 3, d8 = (item & 7) * 8;
        uint4 v = *(const uint4*)&QVR[((long)(b * SEQ + s0 + s)) * 1536 + 512 + h * 64 + d8];
        *(uint2*)&Ls[s * 72 + d8]     = make_uint2(v.x, v.y);
        *(uint2*)&Ls[s * 72 + d8 + 4] = make_uint2(v.z, v.w);
    }
    __syncthreads();
    #pragma unroll
    for (int i = 0; i < 2; i++) {
        int item = t + i * 256;
        int d = item >> 3, sg = item & 7;
        bf16 tmp[8];
        #pragma unroll
        for (int j = 0; j < 8; j++) tmp[j] = Ls[(sg * 8 + j) * 72 + d];
        int sgp = (sg & 4) | ((sg & 3) ^ ((d >> 3) & 3));
        *(uint4*)&VTg[((long)bh * 64 + d) * 2048 + s0 + sgp * 8] = *(uint4*)tmp;
    }
}

// ---------------------------------------------------------------------------
// MFMA flash attention, round-15 = round-14 verified schedule (64-key
// windows, dbuf K/V, prefetch-before-compute, 32-key halves, Kt XOR-swizzle,
// LDS 53248) + XCD-aware block remap (T1). Old mapping: the 8 q-blocks
// sharing one (b,h)'s 512KB K/V panels got consecutive dispatch ids ->
// spread over all 8 XCDs; co-resident blocks per XCD spanned ~96 panels
// (48MB >> 4MB L2) -> prefetches missed L2 (FETCH 139MB vs 64MB unique).
// New: wid=(bid&7)*64+(bid>>3) gives each XCD 8 consecutive bh x all 8
// q-blocks = 4MB working set = one L2. Bijective (512 % 8 == 0).
// ---------------------------------------------------------------------------
__global__ __launch_bounds__(512) void attn_mfma(const bf16* __restrict__ QVR,
                                                 const bf16* __restrict__ VTg,
                                                 bf16* __restrict__ O)
{
    __shared__ bf16 Kt[2][4096];          // [buf][ksd*2048 + key*32 + d^swz]
    __shared__ bf16 Vt[2][4096];          // [buf][half*2048 + d*32 + key'], swizzled
    __shared__ bf16 Pl[8 * 32 * 40];      // per-wave P [qrow][32key], pad 40
    const int tid = threadIdx.x;
    const int w = tid >> 6, lane = tid & 63;
    const int li = lane & 15, quad = lane >> 4;
    // XCD-aware remap: hardware assigns XCD ~ (dispatch id % 8); give each
    // XCD a contiguous 64-work chunk = 8 bh values x 8 q-blocks.
    const int bid = blockIdx.y * 8 + blockIdx.x;   // x fastest
    const int wid = (bid & 7) * 64 + (bid >> 3);
    const int bh = wid >> 3;
    const int b = bh >> 3, hd = bh & 7;
    const int q0 = (wid & 7) * 256;
    const int qw = q0 + w * 32;                    // wave's q base
    const long rowb = (long)b * SEQ;
    const bf16* Qb = QVR + hd * DK;
    const bf16* Hb = QVR + 512 + hd * DK;          // H in V slots
    bf16* Pw = &Pl[w * 32 * 40];
    const f32x4 z4 = {0.f, 0.f, 0.f, 0.f};

    short8 ones;
    #pragma unroll
    for (int i = 0; i < 8; i++) ones[i] = (short)0x3F80;   // bf16 1.0

    // Q as A-operand fragments (verified mapping)
    short8 qa[2][2];
    #pragma unroll
    for (int mt = 0; mt < 2; mt++)
        #pragma unroll
        for (int ks = 0; ks < 2; ks++)
            qa[mt][ks] = *(const short8*)&Qb[(rowb + qw + mt * 16 + li) * 1536
                                             + ks * 32 + quad * 8];

    f32x4 oacc[2][4];
    f32x4 lacc[2];
    #pragma unroll
    for (int mt = 0; mt < 2; mt++) {
        #pragma unroll
        for (int dt = 0; dt < 4; dt++) oacc[mt][dt] = z4;
        lacc[mt] = z4;
    }

    // per-wave staging source pointers (wave 0..3: K/H rows; wave 4..7: V^T)
    // K source col pre-swizzled: slot (lane&3) ^ g, g = (lane>>3)&3
    const bf16* gk = Hb + (rowb + w * 16 + (lane >> 2)) * 1536
                     + (((lane & 3) ^ ((lane >> 3) & 3)) * 8);
    const bf16* gv = VTg + ((long)bh * 64 + (w - 4) * 16 + (lane >> 2)) * 2048
                     + (lane & 3) * 8;
    const int gkr = (li >> 1) & 3;                 // read-side XOR term

    // prologue: stage window 0 into buffer 0
    if (w < 4) {
        async16(&Kt[0][w * 512],        gk);
        async16(&Kt[0][2048 + w * 512], gk + 32);
    } else {
        async16(&Vt[0][(w - 4) * 512],        gv);
        async16(&Vt[0][2048 + (w - 4) * 512], gv + 32);
    }
    gk += (long)64 * 1536;
    gv += 64;
    __syncthreads();

    for (int t = 0; t < 32; t++) {
        const int cb = t & 1, nb = cb ^ 1;

        // ---- prefetch window t+1 into the other buffer (issue-only) ----
        if (t < 31) {
            if (w < 4) {
                async16(&Kt[nb][w * 512],        gk);
                async16(&Kt[nb][2048 + w * 512], gk + 32);
            } else {
                async16(&Vt[nb][(w - 4) * 512],        gv);
                async16(&Vt[nb][2048 + (w - 4) * 512], gv + 32);
            }
            gk += (long)64 * 1536;
            gv += 64;
        }

        const int kt2 = t * 64;
        const bf16* Kp = Kt[cb];
        const bf16* Vp = Vt[cb];

        // ---- two 32-key halves per window (P buffer is half-width) ----
        #pragma unroll
        for (int half = 0; half < 2; half++) {
            const int kt2h = kt2 + half * 32;

            // S = Q K^T for this half's 2 key tiles (full 64-d)
            f32x4 sa[2][2];
            #pragma unroll
            for (int mt = 0; mt < 2; mt++)
                #pragma unroll
                for (int nt = 0; nt < 2; nt++) sa[mt][nt] = z4;
            #pragma unroll
            for (int ksd = 0; ksd < 2; ksd++) {
                short8 kb[2];
                #pragma unroll
                for (int nt = 0; nt < 2; nt++)
                    kb[nt] = *(const short8*)&Kp[ksd * 2048
                               + ((half * 2 + nt) * 16 + li) * 32
                               + ((quad ^ gkr) * 8)];
                #pragma unroll
                for (int mt = 0; mt < 2; mt++)
                    #pragma unroll
                    for (int nt = 0; nt < 2; nt++)
                        sa[mt][nt] = __builtin_amdgcn_mfma_f32_16x16x32_bf16(
                            qa[mt][ksd], kb[nt], sa[mt][nt], 0, 0, 0);
            }

            // p = exp2(s [+ log2e]); write P (32 cols)
            bool nomask  = (kt2h + 31 <= qw);      // max key <= min q
            bool allmask = (kt2h > qw + 31);       // min key > max q
            if (nomask || allmask) {
                float MB = allmask ? MC2 : 0.0f;
                #pragma unroll
                for (int mt = 0; mt < 2; mt++)
                    #pragma unroll
                    for (int nt = 0; nt < 2; nt++) {
                        f32x4 s = sa[mt][nt];
                        #pragma unroll
                        for (int r = 0; r < 4; r++) {
                            float p = __builtin_amdgcn_exp2f(s[r] + MB);
                            Pw[(mt * 16 + quad * 4 + r) * 40 + nt * 16 + li] = f2b(p);
                        }
                    }
            } else {
                #pragma unroll
                for (int mt = 0; mt < 2; mt++) {
                    int qrow = qw + mt * 16 + quad * 4;     // + r below
                    #pragma unroll
                    for (int nt = 0; nt < 2; nt++) {
                        int key = kt2h + nt * 16 + li;
                        f32x4 s = sa[mt][nt];
                        #pragma unroll
                        for (int r = 0; r < 4; r++) {
                            float arg = (key > qrow + r) ? s[r] + MC2 : s[r];
                            float p = __builtin_amdgcn_exp2f(arg);
                            Pw[(mt * 16 + quad * 4 + r) * 40 + nt * 16 + li] = f2b(p);
                        }
                    }
                }
            }

            // O += P V ;  l += P 1 (matrix pipe), keys of this half
            short8 vbf[4], pa[2];
            #pragma unroll
            for (int dt = 0; dt < 4; dt++) {
                int d = dt * 16 + li;
                int sw = ((d >> 3) & 3) << 3;
                vbf[dt] = *(const short8*)&Vp[half * 2048 + d * 32 + ((quad * 8) ^ sw)];
            }
            #pragma unroll
            for (int mt = 0; mt < 2; mt++)
                pa[mt] = *(const short8*)&Pw[(mt * 16 + li) * 40 + quad * 8];
            #pragma unroll
            for (int mt = 0; mt < 2; mt++) {
                lacc[mt] = __builtin_amdgcn_mfma_f32_16x16x32_bf16(
                    pa[mt], ones, lacc[mt], 0, 0, 0);
                #pragma unroll
                for (int dt = 0; dt < 4; dt++)
                    oacc[mt][dt] = __builtin_amdgcn_mfma_f32_16x16x32_bf16(
                        pa[mt], vbf[dt], oacc[mt][dt], 0, 0, 0);
            }
        }

        // one barrier per window: vmcnt(0)+lgkmcnt(0) drain covers the
        // prefetch (which had the whole compute above to complete) and
        // orders the buffer swap (WAR on Kt/Vt[nb] next iteration).
        __syncthreads();
    }

    #pragma unroll
    for (int mt = 0; mt < 2; mt++)
        #pragma unroll
        for (int r = 0; r < 4; r++) {
            float inv = 1.0f / lacc[mt][r];
            long row = rowb + qw + mt * 16 + quad * 4 + r;
            #pragma unroll
            for (int dt = 0; dt < 4; dt++)
                O[row * 512 + hd * 64 + dt * 16 + li] = f2b(oacc[mt][dt][r] * inv);
        }
}

// ---------------------------------------------------------------------------
// LN1: xb + AO (both bf16 plain) -> X1 bf16 plain (u32-vectorized).
// ROUND-5-VERIFIED version (wave-per-row rewrite REGRESSED ~44us, reverted).
// ---------------------------------------------------------------------------
__global__ __launch_bounds__(256) void ln1_kernel(const bf16* __restrict__ xb,
                                                  const bf16* __restrict__ ao,
                                                  const void* __restrict__ g,
                                                  const void* __restrict__ beta,
                                                  bf16* __restrict__ x1,
                                                  const int* __restrict__ flagp)
{
    const int f32 = *flagp;
    long base = (long)blockIdx.x * 512;
    int tid = threadIdx.x;
    int d2 = tid * 2;
    float x0, x1v, a0, a1;
    unpack2(*(const u32*)&xb[base + d2], x0, x1v);
    unpack2(*(const u32*)&ao[base + d2], a0, a1);
    float v0 = x0 + a0, v1 = x1v + a1;
    float s1 = v0 + v1;
    float s2 = v0 * v0 + v1 * v1;
    #pragma unroll
    for (int off = 32; off > 0; off >>= 1) {
        s1 += __shfl_down(s1, off);
        s2 += __shfl_down(s2, off);
    }
    __shared__ float w1[4], w2[4];
    int wid = tid >> 6, lane = tid & 63;
    if (lane == 0) { w1[wid] = s1; w2[wid] = s2; }
    __syncthreads();
    float t1 = w1[0] + w1[1] + w1[2] + w1[3];
    float t2 = w2[0] + w2[1] + w2[2] + w2[3];
    float mu = t1 * (1.0f / DMODEL);
    float var = t2 * (1.0f / DMODEL) - mu * mu;
    float rs = rsqrtf(var + 1e-5f);
    float r0 = (v0 - mu) * rs * ldE(g, d2, f32) + ldE(beta, d2, f32);
    float r1 = (v1 - mu) * rs * ldE(g, d2 + 1, f32) + ldE(beta, d2 + 1, f32);
    *(u32*)&x1[base + d2] = pack2(r0, r1);
}

// ---------------------------------------------------------------------------
// LN2: X1 + FF2 -> d_out (external dtype, (S,B,D) layout).
// ROUND-5-VERIFIED version (wave-per-row rewrite REGRESSED, reverted).
// ---------------------------------------------------------------------------
__global__ __launch_bounds__(256) void ln2_kernel(const bf16* __restrict__ x1,
                                                  const bf16* __restrict__ ff2,
                                                  const void* __restrict__ g,
                                                  const void* __restrict__ beta,
                                                  void* __restrict__ outp,
                                                  const int* __restrict__ flagp)
{
    const int f32 = *flagp;
    int m = blockIdx.x;                 // b*SEQ + s
    int b = m >> 11, s = m & 2047;
    long plain = (long)m * 512;
    long funny = ((long)s * BATCH + b) * 512;
    int tid = threadIdx.x;
    int d2 = tid * 2;
    float x0, x1v, a0, a1;
    unpack2(*(const u32*)&x1[plain + d2], x0, x1v);
    unpack2(*(const u32*)&ff2[plain + d2], a0, a1);
    float v0 = x0 + a0, v1 = x1v + a1;
    float s1 = v0 + v1;
    float s2 = v0 * v0 + v1 * v1;
    #pragma unroll
    for (int off = 32; off > 0; off >>= 1) {
        s1 += __shfl_down(s1, off);
        s2 += __shfl_down(s2, off);
    }
    __shared__ float w1[4], w2[4];
    int wid = tid >> 6, lane = tid & 63;
    if (lane == 0) { w1[wid] = s1; w2[wid] = s2; }
    __syncthreads();
    float t1 = w1[0] + w1[1] + w1[2] + w1[3];
    float t2 = w2[0] + w2[1] + w2[2] + w2[3];
    float mu = t1 * (1.0f / DMODEL);
    float var = t2 * (1.0f / DMODEL) - mu * mu;
    float rs = rsqrtf(var + 1e-5f);
    float r0 = (v0 - mu) * rs * ldE(g, d2, f32) + ldE(beta, d2, f32);
    float r1 = (v1 - mu) * rs * ldE(g, d2 + 1, f32) + ldE(beta, d2 + 1, f32);
    if (f32) {
        ((float*)outp)[funny + d2]     = r0;
        ((float*)outp)[funny + d2 + 1] = r1;
    } else {
        *(u32*)&((bf16*)outp)[funny + d2] = pack2(r0, r1);
    }
}

// ---------------------------------------------------------------------------
extern "C" void kernel_launch(void* const* d_in, const int* in_sizes, int n_in,
                              void* d_out, int out_size, void* d_ws, size_t ws_size,
                              hipStream_t stream)
{
    (void)in_sizes; (void)n_in; (void)out_size; (void)ws_size;
    const void* x = d_in[0];

    // bf16 workspace layout (elements):
    bf16* W    = (bf16*)d_ws;
    bf16* xb   = W;                       // [0, 8M)   dead after LN1
    bf16* QVR  = W + (8u  << 20);         // [8M, 32M) Q|V|R cols; H written into V slots
    bf16* Ob   = W + (32u << 20);         // [32M,40M) dead after Wo gemm
    bf16* VTg  = W + (40u << 20);         // [40M,48M) V^T swizzled, dead after attn
    bf16* AO   = W + (40u << 20);         // same region, written after attn
    bf16* X1   = W + (8u  << 20);         // reuse QVR head, alive until LN2
    bf16* FFH  = W + (16u << 20);         // [16M,48M) after LN1
    bf16* FF2  = W;                       // reuse xb
    int*  flag = (int*)((char*)d_ws + (size_t)96 * 1024 * 1024);
    bf16* Wt   = (bf16*)((char*)d_ws + (size_t)96 * 1024 * 1024 + 16);
    bf16* Wqvr = Wt;                      // [1536][512]
    bf16* Wob  = Wt + 786432;             // [512][512]
    bf16* Wf1t = Wt + 1048576;            // [2048][512]
    bf16* Wf2t = Wt + 2097152;            // [512][2048]
    bf16* bqvr = Wt + 3145728;
    bf16* bob  = Wt + 3147264;
    bf16* bf1b = Wt + 3147776;
    bf16* bf2b = Wt + 3149824;

    dim3 blk(256);
    probe_kernel<<<1, blk, 0, stream>>>(x, flag);
    prep_all<<<16402, blk, 0, stream>>>(
        x, xb,
        d_in[1], d_in[3], d_in[5], d_in[8], d_in[12], d_in[14],
        d_in[2], d_in[4], d_in[6], d_in[9], d_in[13], d_in[15],
        Wqvr, Wob, Wf1t, Wf2t, bqvr, bob, bf1b, bf2b, flag);

    // combined Q|V|R projection: all 1536 output columns in one dispatch
    mfma_gemm<false><<<dim3(128, 12), blk, 0, stream>>>(
        xb, Wqvr, bqvr, QVR, 512, 512, 1536);

    // V^T precompute (swizzled) into VTg — consumes V slots before recur
    vt_kernel<<<dim3(32, 64), blk, 0, stream>>>(QVR, VTg);

    // chunk-parallel recurrence: R (cols 1024..1535) -> H (cols 512..1023)
    recur_par<<<256, blk, 0, stream>>>(QVR, d_in[7], flag);

    // attention: 512-thread blocks, 256 q-rows each, 64-key prefetched
    // windows, XCD-aware block remap
    attn_mfma<<<dim3(8, 64), dim3(512), 0, stream>>>(QVR, VTg, Ob);

    // Wo projection
    mfma_gemm<false><<<dim3(128, 4), blk, 0, stream>>>(Ob, Wob, bob, AO, 512, 512, 512);

    // LN1
    ln1_kernel<<<MROWS, blk, 0, stream>>>(xb, AO, d_in[10], d_in[11], X1, flag);

    // FF1 (relu)
    mfma_gemm<true><<<dim3(128, 16), blk, 0, stream>>>(X1, Wf1t, bf1b, FFH, 512, 512, 2048);

    // FF2
    mfma_gemm<false><<<dim3(128, 4), blk, 0, stream>>>(FFH, Wf2t, bf2b, FF2, 2048, 2048, 512);

    // LN2 -> d_out
    ln2_kernel<<<MROWS, blk, 0, stream>>>(X1, FF2, d_in[16], d_in[17], d_out, flag);
}

// Round 8
// 425.974 us; speedup vs baseline: 1.1044x; 1.0055x over previous
//
#include <hip/hip_runtime.h>
#include <hip/hip_bf16.h>
#include <math.h>

#define SEQ    2048
#define BATCH  8
#define DMODEL 512
#define NHEADS 8
#define DK     64
#define DFF    2048
#define MROWS  16384

typedef __hip_bfloat16 bf16;
typedef unsigned int   u32;
typedef unsigned short u16;
typedef __attribute__((ext_vector_type(8))) short short8;   // 8 bf16 = 4 VGPR
typedef __attribute__((ext_vector_type(4))) float f32x4;

#define LOG2E  1.4426950408889634f
#define LOG2E2 2.8853900817779268f   // 2*log2(e)
#define MC2    1.4426950408889634f   // log2(e) : +1.0-mask in exp2 domain

__device__ __forceinline__ float b2f(bf16 v) { return __bfloat162float(v); }
__device__ __forceinline__ bf16  f2b(float f) { return __float2bfloat16(f); }
__device__ __forceinline__ u16 f2u(float f) { bf16 h = __float2bfloat16(f); return *(u16*)&h; }
__device__ __forceinline__ u32 pack2(float a, float b) {
    return ((u32)f2u(b) << 16) | (u32)f2u(a);
}
__device__ __forceinline__ void unpack2(u32 u, float& a, float& b) {
    a = __uint_as_float(u << 16);
    b = __uint_as_float(u & 0xFFFF0000u);
}
// external-tensor load: dtype decided at runtime by probe flag (0=bf16, 1=fp32)
__device__ __forceinline__ float ldE(const void* p, long off, int f32) {
    return f32 ? ((const float*)p)[off] : b2f(((const bf16*)p)[off]);
}
// async global->LDS, 16B per lane; lds base must be wave-uniform
__device__ __forceinline__ void async16(bf16* lds, const bf16* g) {
    __builtin_amdgcn_global_load_lds(
        (const __attribute__((address_space(1))) void*)g,
        (__attribute__((address_space(3))) void*)lds, 16, 0, 0);
}

// ---------------------------------------------------------------------------
// Dtype probe (verified round 2): flag=1 means fp32 inputs.
// ---------------------------------------------------------------------------
__global__ __launch_bounds__(256) void probe_kernel(const void* __restrict__ x,
                                                    int* __restrict__ flag)
{
    int tid = threadIdx.x;
    const u16* u = (const u16*)x;
    int cnt = 0;
    #pragma unroll
    for (int i = 0; i < 8; i++) {
        u16 e = u[tid * 8 + i];
        float v = __uint_as_float(((u32)e) << 16);
        float a = fabsf(v);
        if (a > 9.313226e-10f && a < 1.0737418e9f) cnt++;
    }
    __shared__ int sh[256];
    sh[tid] = cnt;
    __syncthreads();
    for (int s = 128; s > 0; s >>= 1) {
        if (tid < s) sh[tid] += sh[tid + s];
        __syncthreads();
    }
    if (tid == 0) *flag = (sh[0] < 1700) ? 1 : 0;
}

// ---------------------------------------------------------------------------
// Merged prep: blocks 0..4095 convert x; blocks 4096.. pack weights.
// Wq,bq pre-scaled by log2e (softmax scale folded into Q).
// ---------------------------------------------------------------------------
__global__ __launch_bounds__(256) void prep_all(
    const void* x, bf16* __restrict__ xb,
    const void* Wq, const void* Wv, const void* Wr, const void* Wo,
    const void* Wf1, const void* Wf2,
    const void* bq, const void* bv, const void* br, const void* bo,
    const void* bf1, const void* bf2,
    bf16* __restrict__ Wqvr, bf16* __restrict__ Wob,
    bf16* __restrict__ Wf1t, bf16* __restrict__ Wf2t,
    bf16* __restrict__ bqvr, bf16* __restrict__ bob,
    bf16* __restrict__ bf1b, bf16* __restrict__ bf2b,
    const int* __restrict__ flagp)
{
    const int f32 = *flagp;
    int bid = blockIdx.x;
    if (bid < 4096) {
        int gid = bid * 256 + threadIdx.x;             // 0..1048575
        int row_in = gid >> 6;                         // s*8+b
        int d8 = (gid & 63) * 8;
        int s = row_in >> 3, b = row_in & 7;
        long src = (long)row_in * 512 + d8;
        long dst = ((long)b * SEQ + s) * 512 + d8;
        if (f32) {
            const float* xf = (const float*)x;
            float4 a = *(const float4*)(xf + src);
            float4 c = *(const float4*)(xf + src + 4);
            u32 o[4] = { pack2(a.x,a.y), pack2(a.z,a.w), pack2(c.x,c.y), pack2(c.z,c.w) };
            *(uint4*)(xb + dst) = *(uint4*)o;
        } else {
            *(uint4*)(xb + dst) = *(const uint4*)((const bf16*)x + src);
        }
        return;
    }
    long g = (long)(bid - 4096) * 256 + threadIdx.x;   // < 3150336
    if (g < 786432) {
        if (g < 262144) Wqvr[g] = f2b(ldE(Wq, g, f32) * LOG2E);   // Q scaled
        else if (g < 524288) Wqvr[g] = f2b(ldE(Wv, g & 262143, f32));
        else Wqvr[g] = f2b(ldE(Wr, g & 262143, f32));
    } else if (g < 1048576) {
        long j = g - 786432;
        Wob[j] = f2b(ldE(Wo, j, f32));
    } else if (g < 2097152) {
        long j = g - 1048576;
        long n = j >> 9, k = j & 511;
        Wf1t[j] = f2b(ldE(Wf1, k * 2048 + n, f32));
    } else if (g < 3145728) {
        long j = g - 2097152;
        long n = j >> 11, k = j & 2047;
        Wf2t[j] = f2b(ldE(Wf2, k * 512 + n, f32));
    } else {
        long j = g - 3145728;
        if (j < 512)       bqvr[j]      = f2b(ldE(bq, j, f32) * LOG2E);
        else if (j < 1024) bqvr[j]      = f2b(ldE(bv, j - 512, f32));
        else if (j < 1536) bqvr[j]      = f2b(ldE(br, j - 1024, f32));
        else if (j < 2048) bob[j-1536]  = f2b(ldE(bo, j - 1536, f32));
        else if (j < 4096) bf1b[j-2048] = f2b(ldE(bf1, j - 2048, f32));
        else if (j < 4608) bf2b[j-4096] = f2b(ldE(bf2, j - 4096, f32));
    }
}

// ---------------------------------------------------------------------------
// MFMA GEMM body, BK=64 as two 32-K panels (verified round 7 / round-2 bench;
// BK=32 dbuf prefetch REGRESSED (round 3). Used for QVR proj (6 blocks/CU)
// and FF1 (8 blocks/CU) where 32KB LDS preserves occupancy.
// ---------------------------------------------------------------------------
template<bool RELU>
__device__ __forceinline__ void gemm_body(
    const bf16* __restrict__ A, const bf16* __restrict__ W,
    const bf16* __restrict__ bias, bf16* __restrict__ C,
    int K, int lda, int ldc, int bx, int by, bf16* As, bf16* Bs)
{
    const int tid = threadIdx.x;
    const int w = tid >> 6, lane = tid & 63;
    const int li = lane & 15, quad = lane >> 4;
    const int m0 = bx * 128, n0 = by * 128;
    const int wm = (w >> 1) * 64, wn = (w & 1) * 64;
    const int srow = lane >> 2, scol = (lane & 3) * 8;

    f32x4 acc[4][4];
    const f32x4 z4 = {0.f, 0.f, 0.f, 0.f};
    #pragma unroll
    for (int i = 0; i < 4; i++)
        #pragma unroll
        for (int j = 0; j < 4; j++) acc[i][j] = z4;

    const bf16* ga = A + (long)(m0 + w * 32 + srow) * lda + scol;
    const bf16* gb = W + (long)(n0 + w * 32 + srow) * K + scol;
    bf16* lA0 = &As[(w * 32) * 32];
    bf16* lA1 = &As[(w * 32 + 16) * 32];
    bf16* lB0 = &Bs[(w * 32) * 32];
    bf16* lB1 = &Bs[(w * 32 + 16) * 32];

    for (int k0 = 0; k0 < K; k0 += 64) {
        __syncthreads();
        async16(lA0, ga);
        async16(lA1, ga + (long)16 * lda);
        async16(lA0 + 4096, ga + 32);
        async16(lA1 + 4096, ga + 32 + (long)16 * lda);
        async16(lB0, gb);
        async16(lB1, gb + (long)16 * K);
        async16(lB0 + 4096, gb + 32);
        async16(lB1 + 4096, gb + 32 + (long)16 * K);
        ga += 64; gb += 64;
        __syncthreads();
        #pragma unroll
        for (int ks = 0; ks < 2; ks++) {
            short8 af[4], bfr[4];
            #pragma unroll
            for (int t = 0; t < 4; t++)
                af[t] = *(const short8*)&As[ks * 4096 + (wm + t * 16 + li) * 32 + quad * 8];
            #pragma unroll
            for (int t = 0; t < 4; t++)
                bfr[t] = *(const short8*)&Bs[ks * 4096 + (wn + t * 16 + li) * 32 + quad * 8];
            #pragma unroll
            for (int i = 0; i < 4; i++)
                #pragma unroll
                for (int j = 0; j < 4; j++)
                    acc[i][j] = __builtin_amdgcn_mfma_f32_16x16x32_bf16(
                        af[i], bfr[j], acc[i][j], 0, 0, 0);
        }
    }

    #pragma unroll
    for (int i = 0; i < 4; i++) {
        #pragma unroll
        for (int j = 0; j < 4; j++) {
            int col = n0 + wn + j * 16 + li;
            float bb = b2f(bias[col]);
            #pragma unroll
            for (int r = 0; r < 4; r++) {
                int row = m0 + wm + i * 16 + quad * 4 + r;
                float v = acc[i][j][r] + bb;
                if (RELU) v = fmaxf(v, 0.f);
                C[(long)row * ldc + col] = f2b(v);
            }
        }
    }
}

template<bool RELU>
__global__ __launch_bounds__(256) void mfma_gemm(
    const bf16* __restrict__ A, const bf16* __restrict__ W,
    const bf16* __restrict__ bias, bf16* __restrict__ C,
    int K, int lda, int ldc)
{
    __shared__ bf16 As[8192];
    __shared__ bf16 Bs[8192];
    gemm_body<RELU>(A, W, bias, C, K, lda, ldc, blockIdx.x, blockIdx.y, As, Bs);
}

// ---------------------------------------------------------------------------
// Round-16: prefetched BK=64 double-buffered GEMM for GRID-LIMITED dispatches
// (Wo, FF2: 512 blocks = 2 blocks/CU regardless of LDS, so 64KB LDS is free).
// vs the verified kernel: barrier count HALVED (1 per 64-K step instead of
// 2), and each barrier's vmcnt(0) drains loads that had a full 32-MFMA
// compute phase to land (round-3's BK=32 failure had 16-MFMA phases AND the
// same barrier count — this dominates it on both axes). Math identical.
// DO NOT use for QVR/FF1 (their 5-8 blocks/CU would drop to 2 — m132).
// ---------------------------------------------------------------------------
template<bool RELU>
__global__ __launch_bounds__(256) void mfma_gemm_pf(
    const bf16* __restrict__ A, const bf16* __restrict__ W,
    const bf16* __restrict__ bias, bf16* __restrict__ C,
    int K, int lda, int ldc)
{
    __shared__ bf16 As[2][8192];
    __shared__ bf16 Bs[2][8192];
    const int tid = threadIdx.x;
    const int w = tid >> 6, lane = tid & 63;
    const int li = lane & 15, quad = lane >> 4;
    const int m0 = blockIdx.x * 128, n0 = blockIdx.y * 128;
    const int wm = (w >> 1) * 64, wn = (w & 1) * 64;
    const int srow = lane >> 2, scol = (lane & 3) * 8;

    f32x4 acc[4][4];
    const f32x4 z4 = {0.f, 0.f, 0.f, 0.f};
    #pragma unroll
    for (int i = 0; i < 4; i++)
        #pragma unroll
        for (int j = 0; j < 4; j++) acc[i][j] = z4;

    const bf16* ga = A + (long)(m0 + w * 32 + srow) * lda + scol;
    const bf16* gb = W + (long)(n0 + w * 32 + srow) * K + scol;
    const int aoff0 = (w * 32) * 32;
    const int aoff1 = (w * 32 + 16) * 32;

    // prologue: stage K-panel 0 (64-K tile) into buffer 0
    async16(&As[0][aoff0], ga);
    async16(&As[0][aoff1], ga + (long)16 * lda);
    async16(&As[0][aoff0 + 4096], ga + 32);
    async16(&As[0][aoff1 + 4096], ga + 32 + (long)16 * lda);
    async16(&Bs[0][aoff0], gb);
    async16(&Bs[0][aoff1], gb + (long)16 * K);
    async16(&Bs[0][aoff0 + 4096], gb + 32);
    async16(&Bs[0][aoff1 + 4096], gb + 32 + (long)16 * K);
    ga += 64; gb += 64;
    __syncthreads();

    const int NT = K >> 6;
    for (int t = 0; t < NT; t++) {
        const int cb = t & 1, nb = cb ^ 1;

        // ---- issue next 64-K tile loads first (hide under 32 MFMA) ----
        if (t + 1 < NT) {
            async16(&As[nb][aoff0], ga);
            async16(&As[nb][aoff1], ga + (long)16 * lda);
            async16(&As[nb][aoff0 + 4096], ga + 32);
            async16(&As[nb][aoff1 + 4096], ga + 32 + (long)16 * lda);
            async16(&Bs[nb][aoff0], gb);
            async16(&Bs[nb][aoff1], gb + (long)16 * K);
            async16(&Bs[nb][aoff0 + 4096], gb + 32);
            async16(&Bs[nb][aoff1 + 4096], gb + 32 + (long)16 * K);
            ga += 64; gb += 64;
        }

        // ---- compute current 64-K tile (32 MFMA) ----
        #pragma unroll
        for (int ks = 0; ks < 2; ks++) {
            short8 af[4], bfr[4];
            #pragma unroll
            for (int t4 = 0; t4 < 4; t4++)
                af[t4] = *(const short8*)&As[cb][ks * 4096 + (wm + t4 * 16 + li) * 32 + quad * 8];
            #pragma unroll
            for (int t4 = 0; t4 < 4; t4++)
                bfr[t4] = *(const short8*)&Bs[cb][ks * 4096 + (wn + t4 * 16 + li) * 32 + quad * 8];
            #pragma unroll
            for (int i = 0; i < 4; i++)
                #pragma unroll
                for (int j = 0; j < 4; j++)
                    acc[i][j] = __builtin_amdgcn_mfma_f32_16x16x32_bf16(
                        af[i], bfr[j], acc[i][j], 0, 0, 0);
        }

        // one barrier per 64-K step: drains the prefetch (which had the
        // whole compute above to complete) and orders the buffer swap.
        __syncthreads();
    }

    #pragma unroll
    for (int i = 0; i < 4; i++) {
        #pragma unroll
        for (int j = 0; j < 4; j++) {
            int col = n0 + wn + j * 16 + li;
            float bb = b2f(bias[col]);
            #pragma unroll
            for (int r = 0; r < 4; r++) {
                int row = m0 + wm + i * 16 + quad * 4 + r;
                float v = acc[i][j][r] + bb;
                if (RELU) v = fmaxf(v, 0.f);
                C[(long)row * ldc + col] = f2b(v);
            }
        }
    }
}

// ---------------------------------------------------------------------------
// Parallel chunked recurrence (round-10, verified). Contracting tanh map:
// 64-step warm-up from h=0 reconstructs state below bf16 noise. Serial depth
// 2048 -> 192, threads 4096 -> 65536. Reads R (cols 1024..1535), writes
// H*0.125 into the V slots (cols 512..1023, dead after vt_kernel).
// ---------------------------------------------------------------------------
__global__ __launch_bounds__(256) void recur_par(bf16* __restrict__ QVR,
                                                 const void* __restrict__ Wh,
                                                 const int* __restrict__ flagp)
{
    const int f32 = *flagp;
    const int idx = blockIdx.x * 256 + threadIdx.x;   // 0..65535
    const int k   = idx >> 12;                        // chunk 0..15
    const int rem = idx & 4095;
    const int b   = rem >> 9, o = rem & 511;

    float w = 0.0f;
    #pragma unroll
    for (int j = 0; j < DK; j++) w += ldE(Wh, (long)o * DK + j, f32);
    const float w2 = w * LOG2E2;

    const bf16* rb = QVR + (long)b * SEQ * 1536 + 1024 + o;   // R source
    bf16*       hb = QVR + (long)b * SEQ * 1536 + 512  + o;   // H dest (V slots)

    const int s1   = k * 128;                  // first stored step
    const int s0   = (k == 0) ? 0 : s1 - 64;   // warm-up start
    const int warm = s1 - s0;                  // 0 or 64 (multiple of PF)
    const int TOT  = 128 + warm;               // 128 or 192

    const int PF = 32;
    float buf[PF];
    #pragma unroll
    for (int i = 0; i < PF; i++)
        buf[i] = b2f(rb[(long)(s0 + i) * 1536]) * LOG2E2;

    float h = 0.0f;
    for (int t = 0; t < TOT; t += PF) {
        float nbuf[PF];
        if (t + PF < TOT) {
            #pragma unroll
            for (int i = 0; i < PF; i++)
                nbuf[i] = b2f(rb[(long)(s0 + t + PF + i) * 1536]) * LOG2E2;
        }
        const bool store = (t >= warm);        // block-uniform
        #pragma unroll
        for (int i = 0; i < PF; i++) {
            float xx = fmaf(h, w2, buf[i]);            // 2*log2e*(h*w + r)
            float e  = __builtin_amdgcn_exp2f(xx);
            float d  = __builtin_amdgcn_rcpf(e + 1.0f);
            h = fmaf(-2.0f, d, 1.0f);                  // tanh
            if (store) hb[(long)(s0 + t + i) * 1536] = f2b(h * 0.125f);
        }
        #pragma unroll
        for (int i = 0; i < PF; i++) buf[i] = nbuf[i];
    }
}

// ---------------------------------------------------------------------------
// V^T precompute with pre-applied XOR swizzle (verified round 7/round-2).
// Swizzle permutes 8-key groups WITHIN each 32-key half (sg&4 preserved).
// ---------------------------------------------------------------------------
__global__ __launch_bounds__(256) void vt_kernel(const bf16* __restrict__ QVR,
                                                 bf16* __restrict__ VTg)
{
    __shared__ bf16 Ls[64 * 72];   // [s][d], pad 8
    int bh = blockIdx.y, b = bh >> 3, h = bh & 7;
    int s0 = blockIdx.x * 64;
    int t = threadIdx.x;
    #pragma unroll
    for (int i = 0; i < 2; i++) {
        int item = t + i * 256;
        int s = item >> 3, d8 = (item & 7) * 8;
        uint4 v = *(const uint4*)&QVR[((long)(b * SEQ + s0 + s)) * 1536 + 512 + h * 64 + d8];
        *(uint2*)&Ls[s * 72 + d8]     = make_uint2(v.x, v.y);
        *(uint2*)&Ls[s * 72 + d8 + 4] = make_uint2(v.z, v.w);
    }
    __syncthreads();
    #pragma unroll
    for (int i = 0; i < 2; i++) {
        int item = t + i * 256;
        int d = item >> 3, sg = item & 7;
        bf16 tmp[8];
        #pragma unroll
        for (int j = 0; j < 8; j++) tmp[j] = Ls[(sg * 8 + j) * 72 + d];
        int sgp = (sg & 4) | ((sg & 3) ^ ((d >> 3) & 3));
        *(uint4*)&VTg[((long)bh * 64 + d) * 2048 + s0 + sgp * 8] = *(uint4*)tmp;
    }
}

// ---------------------------------------------------------------------------
// MFMA flash attention (round-15, verified): 64-key windows, dbuf K/V,
// prefetch-before-compute, 32-key halves, Kt XOR-swizzle, XCD-aware remap.
// ---------------------------------------------------------------------------
__global__ __launch_bounds__(512) void attn_mfma(const bf16* __restrict__ QVR,
                                                 const bf16* __restrict__ VTg,
                                                 bf16* __restrict__ O)
{
    __shared__ bf16 Kt[2][4096];          // [buf][ksd*2048 + key*32 + d^swz]
    __shared__ bf16 Vt[2][4096];          // [buf][half*2048 + d*32 + key'], swizzled
    __shared__ bf16 Pl[8 * 32 * 40];      // per-wave P [qrow][32key], pad 40
    const int tid = threadIdx.x;
    const int w = tid >> 6, lane = tid & 63;
    const int li = lane & 15, quad = lane >> 4;
    // XCD-aware remap: hardware assigns XCD ~ (dispatch id % 8); give each
    // XCD a contiguous 64-work chunk = 8 bh values x 8 q-blocks.
    const int bid = blockIdx.y * 8 + blockIdx.x;   // x fastest
    const int wid = (bid & 7) * 64 + (bid >> 3);
    const int bh = wid >> 3;
    const int b = bh >> 3, hd = bh & 7;
    const int q0 = (wid & 7) * 256;
    const int qw = q0 + w * 32;                    // wave's q base
    const long rowb = (long)b * SEQ;
    const bf16* Qb = QVR + hd * DK;
    const bf16* Hb = QVR + 512 + hd * DK;          // H in V slots
    bf16* Pw = &Pl[w * 32 * 40];
    const f32x4 z4 = {0.f, 0.f, 0.f, 0.f};

    short8 ones;
    #pragma unroll
    for (int i = 0; i < 8; i++) ones[i] = (short)0x3F80;   // bf16 1.0

    // Q as A-operand fragments (verified mapping)
    short8 qa[2][2];
    #pragma unroll
    for (int mt = 0; mt < 2; mt++)
        #pragma unroll
        for (int ks = 0; ks < 2; ks++)
            qa[mt][ks] = *(const short8*)&Qb[(rowb + qw + mt * 16 + li) * 1536
                                             + ks * 32 + quad * 8];

    f32x4 oacc[2][4];
    f32x4 lacc[2];
    #pragma unroll
    for (int mt = 0; mt < 2; mt++) {
        #pragma unroll
        for (int dt = 0; dt < 4; dt++) oacc[mt][dt] = z4;
        lacc[mt] = z4;
    }

    // per-wave staging source pointers (wave 0..3: K/H rows; wave 4..7: V^T)
    // K source col pre-swizzled: slot (lane&3) ^ g, g = (lane>>3)&3
    const bf16* gk = Hb + (rowb + w * 16 + (lane >> 2)) * 1536
                     + (((lane & 3) ^ ((lane >> 3) & 3)) * 8);
    const bf16* gv = VTg + ((long)bh * 64 + (w - 4) * 16 + (lane >> 2)) * 2048
                     + (lane & 3) * 8;
    const int gkr = (li >> 1) & 3;                 // read-side XOR term

    // prologue: stage window 0 into buffer 0
    if (w < 4) {
        async16(&Kt[0][w * 512],        gk);
        async16(&Kt[0][2048 + w * 512], gk + 32);
    } else {
        async16(&Vt[0][(w - 4) * 512],        gv);
        async16(&Vt[0][2048 + (w - 4) * 512], gv + 32);
    }
    gk += (long)64 * 1536;
    gv += 64;
    __syncthreads();

    for (int t = 0; t < 32; t++) {
        const int cb = t & 1, nb = cb ^ 1;

        // ---- prefetch window t+1 into the other buffer (issue-only) ----
        if (t < 31) {
            if (w < 4) {
                async16(&Kt[nb][w * 512],        gk);
                async16(&Kt[nb][2048 + w * 512], gk + 32);
            } else {
                async16(&Vt[nb][(w - 4) * 512],        gv);
                async16(&Vt[nb][2048 + (w - 4) * 512], gv + 32);
            }
            gk += (long)64 * 1536;
            gv += 64;
        }

        const int kt2 = t * 64;
        const bf16* Kp = Kt[cb];
        const bf16* Vp = Vt[cb];

        // ---- two 32-key halves per window (P buffer is half-width) ----
        #pragma unroll
        for (int half = 0; half < 2; half++) {
            const int kt2h = kt2 + half * 32;

            // S = Q K^T for this half's 2 key tiles (full 64-d)
            f32x4 sa[2][2];
            #pragma unroll
            for (int mt = 0; mt < 2; mt++)
                #pragma unroll
                for (int nt = 0; nt < 2; nt++) sa[mt][nt] = z4;
            #pragma unroll
            for (int ksd = 0; ksd < 2; ksd++) {
                short8 kb[2];
                #pragma unroll
                for (int nt = 0; nt < 2; nt++)
                    kb[nt] = *(const short8*)&Kp[ksd * 2048
                               + ((half * 2 + nt) * 16 + li) * 32
                               + ((quad ^ gkr) * 8)];
                #pragma unroll
                for (int mt = 0; mt < 2; mt++)
                    #pragma unroll
                    for (int nt = 0; nt < 2; nt++)
                        sa[mt][nt] = __builtin_amdgcn_mfma_f32_16x16x32_bf16(
                            qa[mt][ksd], kb[nt], sa[mt][nt], 0, 0, 0);
            }

            // p = exp2(s [+ log2e]); write P (32 cols)
            bool nomask  = (kt2h + 31 <= qw);      // max key <= min q
            bool allmask = (kt2h > qw + 31);       // min key > max q
            if (nomask || allmask) {
                float MB = allmask ? MC2 : 0.0f;
                #pragma unroll
                for (int mt = 0; mt < 2; mt++)
                    #pragma unroll
                    for (int nt = 0; nt < 2; nt++) {
                        f32x4 s = sa[mt][nt];
                        #pragma unroll
                        for (int r = 0; r < 4; r++) {
                            float p = __builtin_amdgcn_exp2f(s[r] + MB);
                            Pw[(mt * 16 + quad * 4 + r) * 40 + nt * 16 + li] = f2b(p);
                        }
                    }
            } else {
                #pragma unroll
                for (int mt = 0; mt < 2; mt++) {
                    int qrow = qw + mt * 16 + quad * 4;     // + r below
                    #pragma unroll
                    for (int nt = 0; nt < 2; nt++) {
                        int key = kt2h + nt * 16 + li;
                        f32x4 s = sa[mt][nt];
                        #pragma unroll
                        for (int r = 0; r < 4; r++) {
                            float arg = (key > qrow + r) ? s[r] + MC2 : s[r];
                            float p = __builtin_amdgcn_exp2f(arg);
                            Pw[(mt * 16 + quad * 4 + r) * 40 + nt * 16 + li] = f2b(p);
                        }
                    }
                }
            }

            // O += P V ;  l += P 1 (matrix pipe), keys of this half
            short8 vbf[4], pa[2];
            #pragma unroll
            for (int dt = 0; dt < 4; dt++) {
                int d = dt * 16 + li;
                int sw = ((d >> 3) & 3) << 3;
                vbf[dt] = *(const short8*)&Vp[half * 2048 + d * 32 + ((quad * 8) ^ sw)];
            }
            #pragma unroll
            for (int mt = 0; mt < 2; mt++)
                pa[mt] = *(const short8*)&Pw[(mt * 16 + li) * 40 + quad * 8];
            #pragma unroll
            for (int mt = 0; mt < 2; mt++) {
                lacc[mt] = __builtin_amdgcn_mfma_f32_16x16x32_bf16(
                    pa[mt], ones, lacc[mt], 0, 0, 0);
                #pragma unroll
                for (int dt = 0; dt < 4; dt++)
                    oacc[mt][dt] = __builtin_amdgcn_mfma_f32_16x16x32_bf16(
                        pa[mt], vbf[dt], oacc[mt][dt], 0, 0, 0);
            }
        }

        // one barrier per window: vmcnt(0)+lgkmcnt(0) drain covers the
        // prefetch (which had the whole compute above to complete) and
        // orders the buffer swap (WAR on Kt/Vt[nb] next iteration).
        __syncthreads();
    }

    #pragma unroll
    for (int mt = 0; mt < 2; mt++)
        #pragma unroll
        for (int r = 0; r < 4; r++) {
            float inv = 1.0f / lacc[mt][r];
            long row = rowb + qw + mt * 16 + quad * 4 + r;
            #pragma unroll
            for (int dt = 0; dt < 4; dt++)
                O[row * 512 + hd * 64 + dt * 16 + li] = f2b(oacc[mt][dt][r] * inv);
        }
}

// ---------------------------------------------------------------------------
// LN1: xb + AO (both bf16 plain) -> X1 bf16 plain (u32-vectorized).
// ROUND-5-VERIFIED version (wave-per-row rewrite REGRESSED ~44us, reverted).
// ---------------------------------------------------------------------------
__global__ __launch_bounds__(256) void ln1_kernel(const bf16* __restrict__ xb,
                                                  const bf16* __restrict__ ao,
                                                  const void* __restrict__ g,
                                                  const void* __restrict__ beta,
                                                  bf16* __restrict__ x1,
                                                  const int* __restrict__ flagp)
{
    const int f32 = *flagp;
    long base = (long)blockIdx.x * 512;
    int tid = threadIdx.x;
    int d2 = tid * 2;
    float x0, x1v, a0, a1;
    unpack2(*(const u32*)&xb[base + d2], x0, x1v);
    unpack2(*(const u32*)&ao[base + d2], a0, a1);
    float v0 = x0 + a0, v1 = x1v + a1;
    float s1 = v0 + v1;
    float s2 = v0 * v0 + v1 * v1;
    #pragma unroll
    for (int off = 32; off > 0; off >>= 1) {
        s1 += __shfl_down(s1, off);
        s2 += __shfl_down(s2, off);
    }
    __shared__ float w1[4], w2[4];
    int wid = tid >> 6, lane = tid & 63;
    if (lane == 0) { w1[wid] = s1; w2[wid] = s2; }
    __syncthreads();
    float t1 = w1[0] + w1[1] + w1[2] + w1[3];
    float t2 = w2[0] + w2[1] + w2[2] + w2[3];
    float mu = t1 * (1.0f / DMODEL);
    float var = t2 * (1.0f / DMODEL) - mu * mu;
    float rs = rsqrtf(var + 1e-5f);
    float r0 = (v0 - mu) * rs * ldE(g, d2, f32) + ldE(beta, d2, f32);
    float r1 = (v1 - mu) * rs * ldE(g, d2 + 1, f32) + ldE(beta, d2 + 1, f32);
    *(u32*)&x1[base + d2] = pack2(r0, r1);
}

// ---------------------------------------------------------------------------
// LN2: X1 + FF2 -> d_out (external dtype, (S,B,D) layout).
// ROUND-5-VERIFIED version (wave-per-row rewrite REGRESSED, reverted).
// ---------------------------------------------------------------------------
__global__ __launch_bounds__(256) void ln2_kernel(const bf16* __restrict__ x1,
                                                  const bf16* __restrict__ ff2,
                                                  const void* __restrict__ g,
                                                  const void* __restrict__ beta,
                                                  void* __restrict__ outp,
                                                  const int* __restrict__ flagp)
{
    const int f32 = *flagp;
    int m = blockIdx.x;                 // b*SEQ + s
    int b = m >> 11, s = m & 2047;
    long plain = (long)m * 512;
    long funny = ((long)s * BATCH + b) * 512;
    int tid = threadIdx.x;
    int d2 = tid * 2;
    float x0, x1v, a0, a1;
    unpack2(*(const u32*)&x1[plain + d2], x0, x1v);
    unpack2(*(const u32*)&ff2[plain + d2], a0, a1);
    float v0 = x0 + a0, v1 = x1v + a1;
    float s1 = v0 + v1;
    float s2 = v0 * v0 + v1 * v1;
    #pragma unroll
    for (int off = 32; off > 0; off >>= 1) {
        s1 += __shfl_down(s1, off);
        s2 += __shfl_down(s2, off);
    }
    __shared__ float w1[4], w2[4];
    int wid = tid >> 6, lane = tid & 63;
    if (lane == 0) { w1[wid] = s1; w2[wid] = s2; }
    __syncthreads();
    float t1 = w1[0] + w1[1] + w1[2] + w1[3];
    float t2 = w2[0] + w2[1] + w2[2] + w2[3];
    float mu = t1 * (1.0f / DMODEL);
    float var = t2 * (1.0f / DMODEL) - mu * mu;
    float rs = rsqrtf(var + 1e-5f);
    float r0 = (v0 - mu) * rs * ldE(g, d2, f32) + ldE(beta, d2, f32);
    float r1 = (v1 - mu) * rs * ldE(g, d2 + 1, f32) + ldE(beta, d2 + 1, f32);
    if (f32) {
        ((float*)outp)[funny + d2]     = r0;
        ((float*)outp)[funny + d2 + 1] = r1;
    } else {
        *(u32*)&((bf16*)outp)[funny + d2] = pack2(r0, r1);
    }
}

// ---------------------------------------------------------------------------
extern "C" void kernel_launch(void* const* d_in, const int* in_sizes, int n_in,
                              void* d_out, int out_size, void* d_ws, size_t ws_size,
                              hipStream_t stream)
{
    (void)in_sizes; (void)n_in; (void)out_size; (void)ws_size;
    const void* x = d_in[0];

    // bf16 workspace layout (elements):
    bf16* W    = (bf16*)d_ws;
    bf16* xb   = W;                       // [0, 8M)   dead after LN1
    bf16* QVR  = W + (8u  << 20);         // [8M, 32M) Q|V|R cols; H written into V slots
    bf16* Ob   = W + (32u << 20);         // [32M,40M) dead after Wo gemm
    bf16* VTg  = W + (40u << 20);         // [40M,48M) V^T swizzled, dead after attn
    bf16* AO   = W + (40u << 20);         // same region, written after attn
    bf16* X1   = W + (8u  << 20);         // reuse QVR head, alive until LN2
    bf16* FFH  = W + (16u << 20);         // [16M,48M) after LN1
    bf16* FF2  = W;                       // reuse xb
    int*  flag = (int*)((char*)d_ws + (size_t)96 * 1024 * 1024);
    bf16* Wt   = (bf16*)((char*)d_ws + (size_t)96 * 1024 * 1024 + 16);
    bf16* Wqvr = Wt;                      // [1536][512]
    bf16* Wob  = Wt + 786432;             // [512][512]
    bf16* Wf1t = Wt + 1048576;            // [2048][512]
    bf16* Wf2t = Wt + 2097152;            // [512][2048]
    bf16* bqvr = Wt + 3145728;
    bf16* bob  = Wt + 3147264;
    bf16* bf1b = Wt + 3147776;
    bf16* bf2b = Wt + 3149824;

    dim3 blk(256);
    probe_kernel<<<1, blk, 0, stream>>>(x, flag);
    prep_all<<<16402, blk, 0, stream>>>(
        x, xb,
        d_in[1], d_in[3], d_in[5], d_in[8], d_in[12], d_in[14],
        d_in[2], d_in[4], d_in[6], d_in[9], d_in[13], d_in[15],
        Wqvr, Wob, Wf1t, Wf2t, bqvr, bob, bf1b, bf2b, flag);

    // combined Q|V|R projection: all 1536 output columns in one dispatch
    mfma_gemm<false><<<dim3(128, 12), blk, 0, stream>>>(
        xb, Wqvr, bqvr, QVR, 512, 512, 1536);

    // V^T precompute (swizzled) into VTg — consumes V slots before recur
    vt_kernel<<<dim3(32, 64), blk, 0, stream>>>(QVR, VTg);

    // chunk-parallel recurrence: R (cols 1024..1535) -> H (cols 512..1023)
    recur_par<<<256, blk, 0, stream>>>(QVR, d_in[7], flag);

    // attention: 512-thread blocks, 256 q-rows each, 64-key prefetched
    // windows, XCD-aware block remap
    attn_mfma<<<dim3(8, 64), dim3(512), 0, stream>>>(QVR, VTg, Ob);

    // Wo projection (grid-limited 512 blocks -> prefetched 64KB-LDS variant)
    mfma_gemm_pf<false><<<dim3(128, 4), blk, 0, stream>>>(Ob, Wob, bob, AO, 512, 512, 512);

    // LN1
    ln1_kernel<<<MROWS, blk, 0, stream>>>(xb, AO, d_in[10], d_in[11], X1, flag);

    // FF1 (relu)
    mfma_gemm<true><<<dim3(128, 16), blk, 0, stream>>>(X1, Wf1t, bf1b, FFH, 512, 512, 2048);

    // FF2 (grid-limited 512 blocks -> prefetched 64KB-LDS variant)
    mfma_gemm_pf<false><<<dim3(128, 4), blk, 0, stream>>>(FFH, Wf2t, bf2b, FF2, 2048, 2048, 512);

    // LN2 -> d_out
    ln2_kernel<<<MROWS, blk, 0, stream>>>(X1, FF2, d_in[16], d_in[17], d_out, flag);
}

// Round 9
// 419.747 us; speedup vs baseline: 1.1208x; 1.0148x over previous
//
#include <hip/hip_runtime.h>
#include <hip/hip_bf16.h>
#include <math.h>

#define SEQ    2048
#define BATCH  8
#define DMODEL 512
#define NHEADS 8
#define DK     64
#define DFF    2048
#define MROWS  16384

typedef __hip_bfloat16 bf16;
typedef unsigned int   u32;
typedef unsigned short u16;
typedef __attribute__((ext_vector_type(8))) short short8;   // 8 bf16 = 4 VGPR
typedef __attribute__((ext_vector_type(4))) float f32x4;

#define LOG2E  1.4426950408889634f
#define LOG2E2 2.8853900817779268f   // 2*log2(e)
#define MC2    1.4426950408889634f   // log2(e) : +1.0-mask in exp2 domain

__device__ __forceinline__ float b2f(bf16 v) { return __bfloat162float(v); }
__device__ __forceinline__ bf16  f2b(float f) { return __float2bfloat16(f); }
__device__ __forceinline__ u16 f2u(float f) { bf16 h = __float2bfloat16(f); return *(u16*)&h; }
__device__ __forceinline__ u32 pack2(float a, float b) {
    return ((u32)f2u(b) << 16) | (u32)f2u(a);
}
__device__ __forceinline__ void unpack2(u32 u, float& a, float& b) {
    a = __uint_as_float(u << 16);
    b = __uint_as_float(u & 0xFFFF0000u);
}
// external-tensor load: dtype decided at runtime by probe flag (0=bf16, 1=fp32)
__device__ __forceinline__ float ldE(const void* p, long off, int f32) {
    return f32 ? ((const float*)p)[off] : b2f(((const bf16*)p)[off]);
}
// async global->LDS, 16B per lane; lds base must be wave-uniform
__device__ __forceinline__ void async16(bf16* lds, const bf16* g) {
    __builtin_amdgcn_global_load_lds(
        (const __attribute__((address_space(1))) void*)g,
        (__attribute__((address_space(3))) void*)lds, 16, 0, 0);
}

// ---------------------------------------------------------------------------
// Dtype probe (verified round 2): flag=1 means fp32 inputs.
// ---------------------------------------------------------------------------
__global__ __launch_bounds__(256) void probe_kernel(const void* __restrict__ x,
                                                    int* __restrict__ flag)
{
    int tid = threadIdx.x;
    const u16* u = (const u16*)x;
    int cnt = 0;
    #pragma unroll
    for (int i = 0; i < 8; i++) {
        u16 e = u[tid * 8 + i];
        float v = __uint_as_float(((u32)e) << 16);
        float a = fabsf(v);
        if (a > 9.313226e-10f && a < 1.0737418e9f) cnt++;
    }
    __shared__ int sh[256];
    sh[tid] = cnt;
    __syncthreads();
    for (int s = 128; s > 0; s >>= 1) {
        if (tid < s) sh[tid] += sh[tid + s];
        __syncthreads();
    }
    if (tid == 0) *flag = (sh[0] < 1700) ? 1 : 0;
}

// ---------------------------------------------------------------------------
// Merged prep: blocks 0..4095 convert x; blocks 4096.. pack weights.
// Wq,bq pre-scaled by log2e (softmax scale folded into Q).
// ---------------------------------------------------------------------------
__global__ __launch_bounds__(256) void prep_all(
    const void* x, bf16* __restrict__ xb,
    const void* Wq, const void* Wv, const void* Wr, const void* Wo,
    const void* Wf1, const void* Wf2,
    const void* bq, const void* bv, const void* br, const void* bo,
    const void* bf1, const void* bf2,
    bf16* __restrict__ Wqvr, bf16* __restrict__ Wob,
    bf16* __restrict__ Wf1t, bf16* __restrict__ Wf2t,
    bf16* __restrict__ bqvr, bf16* __restrict__ bob,
    bf16* __restrict__ bf1b, bf16* __restrict__ bf2b,
    const int* __restrict__ flagp)
{
    const int f32 = *flagp;
    int bid = blockIdx.x;
    if (bid < 4096) {
        int gid = bid * 256 + threadIdx.x;             // 0..1048575
        int row_in = gid >> 6;                         // s*8+b
        int d8 = (gid & 63) * 8;
        int s = row_in >> 3, b = row_in & 7;
        long src = (long)row_in * 512 + d8;
        long dst = ((long)b * SEQ + s) * 512 + d8;
        if (f32) {
            const float* xf = (const float*)x;
            float4 a = *(const float4*)(xf + src);
            float4 c = *(const float4*)(xf + src + 4);
            u32 o[4] = { pack2(a.x,a.y), pack2(a.z,a.w), pack2(c.x,c.y), pack2(c.z,c.w) };
            *(uint4*)(xb + dst) = *(uint4*)o;
        } else {
            *(uint4*)(xb + dst) = *(const uint4*)((const bf16*)x + src);
        }
        return;
    }
    long g = (long)(bid - 4096) * 256 + threadIdx.x;   // < 3150336
    if (g < 786432) {
        if (g < 262144) Wqvr[g] = f2b(ldE(Wq, g, f32) * LOG2E);   // Q scaled
        else if (g < 524288) Wqvr[g] = f2b(ldE(Wv, g & 262143, f32));
        else Wqvr[g] = f2b(ldE(Wr, g & 262143, f32));
    } else if (g < 1048576) {
        long j = g - 786432;
        Wob[j] = f2b(ldE(Wo, j, f32));
    } else if (g < 2097152) {
        long j = g - 1048576;
        long n = j >> 9, k = j & 511;
        Wf1t[j] = f2b(ldE(Wf1, k * 2048 + n, f32));
    } else if (g < 3145728) {
        long j = g - 2097152;
        long n = j >> 11, k = j & 2047;
        Wf2t[j] = f2b(ldE(Wf2, k * 512 + n, f32));
    } else {
        long j = g - 3145728;
        if (j < 512)       bqvr[j]      = f2b(ldE(bq, j, f32) * LOG2E);
        else if (j < 1024) bqvr[j]      = f2b(ldE(bv, j - 512, f32));
        else if (j < 1536) bqvr[j]      = f2b(ldE(br, j - 1024, f32));
        else if (j < 2048) bob[j-1536]  = f2b(ldE(bo, j - 1536, f32));
        else if (j < 4096) bf1b[j-2048] = f2b(ldE(bf1, j - 2048, f32));
        else if (j < 4608) bf2b[j-4096] = f2b(ldE(bf2, j - 4096, f32));
    }
}

// ---------------------------------------------------------------------------
// MFMA GEMM body, BK=64 as two 32-K panels (verified round 7 / round-2 bench;
// BK=32 dbuf prefetch REGRESSED (round 3). Used for QVR proj and FF1 where
// 32KB LDS preserves 4-5 blocks/CU (TLP hides the barrier drains).
// ---------------------------------------------------------------------------
template<bool RELU>
__device__ __forceinline__ void gemm_body(
    const bf16* __restrict__ A, const bf16* __restrict__ W,
    const bf16* __restrict__ bias, bf16* __restrict__ C,
    int K, int lda, int ldc, int bx, int by, bf16* As, bf16* Bs)
{
    const int tid = threadIdx.x;
    const int w = tid >> 6, lane = tid & 63;
    const int li = lane & 15, quad = lane >> 4;
    const int m0 = bx * 128, n0 = by * 128;
    const int wm = (w >> 1) * 64, wn = (w & 1) * 64;
    const int srow = lane >> 2, scol = (lane & 3) * 8;

    f32x4 acc[4][4];
    const f32x4 z4 = {0.f, 0.f, 0.f, 0.f};
    #pragma unroll
    for (int i = 0; i < 4; i++)
        #pragma unroll
        for (int j = 0; j < 4; j++) acc[i][j] = z4;

    const bf16* ga = A + (long)(m0 + w * 32 + srow) * lda + scol;
    const bf16* gb = W + (long)(n0 + w * 32 + srow) * K + scol;
    bf16* lA0 = &As[(w * 32) * 32];
    bf16* lA1 = &As[(w * 32 + 16) * 32];
    bf16* lB0 = &Bs[(w * 32) * 32];
    bf16* lB1 = &Bs[(w * 32 + 16) * 32];

    for (int k0 = 0; k0 < K; k0 += 64) {
        __syncthreads();
        async16(lA0, ga);
        async16(lA1, ga + (long)16 * lda);
        async16(lA0 + 4096, ga + 32);
        async16(lA1 + 4096, ga + 32 + (long)16 * lda);
        async16(lB0, gb);
        async16(lB1, gb + (long)16 * K);
        async16(lB0 + 4096, gb + 32);
        async16(lB1 + 4096, gb + 32 + (long)16 * K);
        ga += 64; gb += 64;
        __syncthreads();
        #pragma unroll
        for (int ks = 0; ks < 2; ks++) {
            short8 af[4], bfr[4];
            #pragma unroll
            for (int t = 0; t < 4; t++)
                af[t] = *(const short8*)&As[ks * 4096 + (wm + t * 16 + li) * 32 + quad * 8];
            #pragma unroll
            for (int t = 0; t < 4; t++)
                bfr[t] = *(const short8*)&Bs[ks * 4096 + (wn + t * 16 + li) * 32 + quad * 8];
            #pragma unroll
            for (int i = 0; i < 4; i++)
                #pragma unroll
                for (int j = 0; j < 4; j++)
                    acc[i][j] = __builtin_amdgcn_mfma_f32_16x16x32_bf16(
                        af[i], bfr[j], acc[i][j], 0, 0, 0);
        }
    }

    #pragma unroll
    for (int i = 0; i < 4; i++) {
        #pragma unroll
        for (int j = 0; j < 4; j++) {
            int col = n0 + wn + j * 16 + li;
            float bb = b2f(bias[col]);
            #pragma unroll
            for (int r = 0; r < 4; r++) {
                int row = m0 + wm + i * 16 + quad * 4 + r;
                float v = acc[i][j][r] + bb;
                if (RELU) v = fmaxf(v, 0.f);
                C[(long)row * ldc + col] = f2b(v);
            }
        }
    }
}

template<bool RELU>
__global__ __launch_bounds__(256) void mfma_gemm(
    const bf16* __restrict__ A, const bf16* __restrict__ W,
    const bf16* __restrict__ bias, bf16* __restrict__ C,
    int K, int lda, int ldc)
{
    __shared__ bf16 As[8192];
    __shared__ bf16 Bs[8192];
    gemm_body<RELU>(A, W, bias, C, K, lda, ldc, blockIdx.x, blockIdx.y, As, Bs);
}

// ---------------------------------------------------------------------------
// Prefetched BK=64 double-buffered GEMM for GRID-LIMITED dispatches
// (Wo, FF2: 512 blocks = 2 blocks/CU regardless of LDS, so 64KB LDS free).
// Verified round 7 (small win). DO NOT use for QVR/FF1 (m132 occupancy).
// ---------------------------------------------------------------------------
template<bool RELU>
__global__ __launch_bounds__(256) void mfma_gemm_pf(
    const bf16* __restrict__ A, const bf16* __restrict__ W,
    const bf16* __restrict__ bias, bf16* __restrict__ C,
    int K, int lda, int ldc)
{
    __shared__ bf16 As[2][8192];
    __shared__ bf16 Bs[2][8192];
    const int tid = threadIdx.x;
    const int w = tid >> 6, lane = tid & 63;
    const int li = lane & 15, quad = lane >> 4;
    const int m0 = blockIdx.x * 128, n0 = blockIdx.y * 128;
    const int wm = (w >> 1) * 64, wn = (w & 1) * 64;
    const int srow = lane >> 2, scol = (lane & 3) * 8;

    f32x4 acc[4][4];
    const f32x4 z4 = {0.f, 0.f, 0.f, 0.f};
    #pragma unroll
    for (int i = 0; i < 4; i++)
        #pragma unroll
        for (int j = 0; j < 4; j++) acc[i][j] = z4;

    const bf16* ga = A + (long)(m0 + w * 32 + srow) * lda + scol;
    const bf16* gb = W + (long)(n0 + w * 32 + srow) * K + scol;
    const int aoff0 = (w * 32) * 32;
    const int aoff1 = (w * 32 + 16) * 32;

    // prologue: stage K-panel 0 (64-K tile) into buffer 0
    async16(&As[0][aoff0], ga);
    async16(&As[0][aoff1], ga + (long)16 * lda);
    async16(&As[0][aoff0 + 4096], ga + 32);
    async16(&As[0][aoff1 + 4096], ga + 32 + (long)16 * lda);
    async16(&Bs[0][aoff0], gb);
    async16(&Bs[0][aoff1], gb + (long)16 * K);
    async16(&Bs[0][aoff0 + 4096], gb + 32);
    async16(&Bs[0][aoff1 + 4096], gb + 32 + (long)16 * K);
    ga += 64; gb += 64;
    __syncthreads();

    const int NT = K >> 6;
    for (int t = 0; t < NT; t++) {
        const int cb = t & 1, nb = cb ^ 1;

        // ---- issue next 64-K tile loads first (hide under 32 MFMA) ----
        if (t + 1 < NT) {
            async16(&As[nb][aoff0], ga);
            async16(&As[nb][aoff1], ga + (long)16 * lda);
            async16(&As[nb][aoff0 + 4096], ga + 32);
            async16(&As[nb][aoff1 + 4096], ga + 32 + (long)16 * lda);
            async16(&Bs[nb][aoff0], gb);
            async16(&Bs[nb][aoff1], gb + (long)16 * K);
            async16(&Bs[nb][aoff0 + 4096], gb + 32);
            async16(&Bs[nb][aoff1 + 4096], gb + 32 + (long)16 * K);
            ga += 64; gb += 64;
        }

        // ---- compute current 64-K tile (32 MFMA) ----
        #pragma unroll
        for (int ks = 0; ks < 2; ks++) {
            short8 af[4], bfr[4];
            #pragma unroll
            for (int t4 = 0; t4 < 4; t4++)
                af[t4] = *(const short8*)&As[cb][ks * 4096 + (wm + t4 * 16 + li) * 32 + quad * 8];
            #pragma unroll
            for (int t4 = 0; t4 < 4; t4++)
                bfr[t4] = *(const short8*)&Bs[cb][ks * 4096 + (wn + t4 * 16 + li) * 32 + quad * 8];
            #pragma unroll
            for (int i = 0; i < 4; i++)
                #pragma unroll
                for (int j = 0; j < 4; j++)
                    acc[i][j] = __builtin_amdgcn_mfma_f32_16x16x32_bf16(
                        af[i], bfr[j], acc[i][j], 0, 0, 0);
        }

        // one barrier per 64-K step: drains the prefetch (which had the
        // whole compute above to complete) and orders the buffer swap.
        __syncthreads();
    }

    #pragma unroll
    for (int i = 0; i < 4; i++) {
        #pragma unroll
        for (int j = 0; j < 4; j++) {
            int col = n0 + wn + j * 16 + li;
            float bb = b2f(bias[col]);
            #pragma unroll
            for (int r = 0; r < 4; r++) {
                int row = m0 + wm + i * 16 + quad * 4 + r;
                float v = acc[i][j][r] + bb;
                if (RELU) v = fmaxf(v, 0.f);
                C[(long)row * ldc + col] = f2b(v);
            }
        }
    }
}

// ---------------------------------------------------------------------------
// Parallel chunked recurrence (round-10, verified). Contracting tanh map:
// 64-step warm-up from h=0 reconstructs state below bf16 noise. Serial depth
// 2048 -> 192, threads 4096 -> 65536. Reads R (cols 1024..1535), writes
// H*0.125 into the V slots (cols 512..1023, dead after vt_kernel).
// ---------------------------------------------------------------------------
__global__ __launch_bounds__(256) void recur_par(bf16* __restrict__ QVR,
                                                 const void* __restrict__ Wh,
                                                 const int* __restrict__ flagp)
{
    const int f32 = *flagp;
    const int idx = blockIdx.x * 256 + threadIdx.x;   // 0..65535
    const int k   = idx >> 12;                        // chunk 0..15
    const int rem = idx & 4095;
    const int b   = rem >> 9, o = rem & 511;

    float w = 0.0f;
    #pragma unroll
    for (int j = 0; j < DK; j++) w += ldE(Wh, (long)o * DK + j, f32);
    const float w2 = w * LOG2E2;

    const bf16* rb = QVR + (long)b * SEQ * 1536 + 1024 + o;   // R source
    bf16*       hb = QVR + (long)b * SEQ * 1536 + 512  + o;   // H dest (V slots)

    const int s1   = k * 128;                  // first stored step
    const int s0   = (k == 0) ? 0 : s1 - 64;   // warm-up start
    const int warm = s1 - s0;                  // 0 or 64 (multiple of PF)
    const int TOT  = 128 + warm;               // 128 or 192

    const int PF = 32;
    float buf[PF];
    #pragma unroll
    for (int i = 0; i < PF; i++)
        buf[i] = b2f(rb[(long)(s0 + i) * 1536]) * LOG2E2;

    float h = 0.0f;
    for (int t = 0; t < TOT; t += PF) {
        float nbuf[PF];
        if (t + PF < TOT) {
            #pragma unroll
            for (int i = 0; i < PF; i++)
                nbuf[i] = b2f(rb[(long)(s0 + t + PF + i) * 1536]) * LOG2E2;
        }
        const bool store = (t >= warm);        // block-uniform
        #pragma unroll
        for (int i = 0; i < PF; i++) {
            float xx = fmaf(h, w2, buf[i]);            // 2*log2e*(h*w + r)
            float e  = __builtin_amdgcn_exp2f(xx);
            float d  = __builtin_amdgcn_rcpf(e + 1.0f);
            h = fmaf(-2.0f, d, 1.0f);                  // tanh
            if (store) hb[(long)(s0 + t + i) * 1536] = f2b(h * 0.125f);
        }
        #pragma unroll
        for (int i = 0; i < PF; i++) buf[i] = nbuf[i];
    }
}

// ---------------------------------------------------------------------------
// V^T precompute with pre-applied XOR swizzle (verified round 7/round-2).
// Swizzle permutes 8-key groups WITHIN each 32-key half (sg&4 preserved).
// ---------------------------------------------------------------------------
__global__ __launch_bounds__(256) void vt_kernel(const bf16* __restrict__ QVR,
                                                 bf16* __restrict__ VTg)
{
    __shared__ bf16 Ls[64 * 72];   // [s][d], pad 8
    int bh = blockIdx.y, b = bh >> 3, h = bh & 7;
    int s0 = blockIdx.x * 64;
    int t = threadIdx.x;
    #pragma unroll
    for (int i = 0; i < 2; i++) {
        int item = t + i * 256;
        int s = item >> 3, d8 = (item & 7) * 8;
        uint4 v = *(const uint4*)&QVR[((long)(b * SEQ + s0 + s)) * 1536 + 512 + h * 64 + d8];
        *(uint2*)&Ls[s * 72 + d8]     = make_uint2(v.x, v.y);
        *(uint2*)&Ls[s * 72 + d8 + 4] = make_uint2(v.z, v.w);
    }
    __syncthreads();
    #pragma unroll
    for (int i = 0; i < 2; i++) {
        int item = t + i * 256;
        int d = item >> 3, sg = item & 7;
        bf16 tmp[8];
        #pragma unroll
        for (int j = 0; j < 8; j++) tmp[j] = Ls[(sg * 8 + j) * 72 + d];
        int sgp = (sg & 4) | ((sg & 3) ^ ((d >> 3) & 3));
        *(uint4*)&VTg[((long)bh * 64 + d) * 2048 + s0 + sgp * 8] = *(uint4*)tmp;
    }
}

// ---------------------------------------------------------------------------
// MFMA flash attention, round-17 = round-15 verified schedule (64-key
// windows, dbuf K/V, prefetch-before-compute, 32-key halves, Kt XOR-swizzle,
// XCD-aware remap) + T5 s_setprio(1) around the MFMA clusters. Structure-
// conditional technique: our 8 waves have role diversity (K-staging vs
// V-staging vs compute phases), so priority lets MFMA-entering waves win
// issue slots over staging/exp2 waves (m191: +4-7% on attn).
// ---------------------------------------------------------------------------
__global__ __launch_bounds__(512) void attn_mfma(const bf16* __restrict__ QVR,
                                                 const bf16* __restrict__ VTg,
                                                 bf16* __restrict__ O)
{
    __shared__ bf16 Kt[2][4096];          // [buf][ksd*2048 + key*32 + d^swz]
    __shared__ bf16 Vt[2][4096];          // [buf][half*2048 + d*32 + key'], swizzled
    __shared__ bf16 Pl[8 * 32 * 40];      // per-wave P [qrow][32key], pad 40
    const int tid = threadIdx.x;
    const int w = tid >> 6, lane = tid & 63;
    const int li = lane & 15, quad = lane >> 4;
    // XCD-aware remap: hardware assigns XCD ~ (dispatch id % 8); give each
    // XCD a contiguous 64-work chunk = 8 bh values x 8 q-blocks.
    const int bid = blockIdx.y * 8 + blockIdx.x;   // x fastest
    const int wid = (bid & 7) * 64 + (bid >> 3);
    const int bh = wid >> 3;
    const int b = bh >> 3, hd = bh & 7;
    const int q0 = (wid & 7) * 256;
    const int qw = q0 + w * 32;                    // wave's q base
    const long rowb = (long)b * SEQ;
    const bf16* Qb = QVR + hd * DK;
    const bf16* Hb = QVR + 512 + hd * DK;          // H in V slots
    bf16* Pw = &Pl[w * 32 * 40];
    const f32x4 z4 = {0.f, 0.f, 0.f, 0.f};

    short8 ones;
    #pragma unroll
    for (int i = 0; i < 8; i++) ones[i] = (short)0x3F80;   // bf16 1.0

    // Q as A-operand fragments (verified mapping)
    short8 qa[2][2];
    #pragma unroll
    for (int mt = 0; mt < 2; mt++)
        #pragma unroll
        for (int ks = 0; ks < 2; ks++)
            qa[mt][ks] = *(const short8*)&Qb[(rowb + qw + mt * 16 + li) * 1536
                                             + ks * 32 + quad * 8];

    f32x4 oacc[2][4];
    f32x4 lacc[2];
    #pragma unroll
    for (int mt = 0; mt < 2; mt++) {
        #pragma unroll
        for (int dt = 0; dt < 4; dt++) oacc[mt][dt] = z4;
        lacc[mt] = z4;
    }

    // per-wave staging source pointers (wave 0..3: K/H rows; wave 4..7: V^T)
    // K source col pre-swizzled: slot (lane&3) ^ g, g = (lane>>3)&3
    const bf16* gk = Hb + (rowb + w * 16 + (lane >> 2)) * 1536
                     + (((lane & 3) ^ ((lane >> 3) & 3)) * 8);
    const bf16* gv = VTg + ((long)bh * 64 + (w - 4) * 16 + (lane >> 2)) * 2048
                     + (lane & 3) * 8;
    const int gkr = (li >> 1) & 3;                 // read-side XOR term

    // prologue: stage window 0 into buffer 0
    if (w < 4) {
        async16(&Kt[0][w * 512],        gk);
        async16(&Kt[0][2048 + w * 512], gk + 32);
    } else {
        async16(&Vt[0][(w - 4) * 512],        gv);
        async16(&Vt[0][2048 + (w - 4) * 512], gv + 32);
    }
    gk += (long)64 * 1536;
    gv += 64;
    __syncthreads();

    for (int t = 0; t < 32; t++) {
        const int cb = t & 1, nb = cb ^ 1;

        // ---- prefetch window t+1 into the other buffer (issue-only) ----
        if (t < 31) {
            if (w < 4) {
                async16(&Kt[nb][w * 512],        gk);
                async16(&Kt[nb][2048 + w * 512], gk + 32);
            } else {
                async16(&Vt[nb][(w - 4) * 512],        gv);
                async16(&Vt[nb][2048 + (w - 4) * 512], gv + 32);
            }
            gk += (long)64 * 1536;
            gv += 64;
        }

        const int kt2 = t * 64;
        const bf16* Kp = Kt[cb];
        const bf16* Vp = Vt[cb];

        // ---- two 32-key halves per window (P buffer is half-width) ----
        #pragma unroll
        for (int half = 0; half < 2; half++) {
            const int kt2h = kt2 + half * 32;

            // S = Q K^T for this half's 2 key tiles (full 64-d)
            f32x4 sa[2][2];
            #pragma unroll
            for (int mt = 0; mt < 2; mt++)
                #pragma unroll
                for (int nt = 0; nt < 2; nt++) sa[mt][nt] = z4;
            #pragma unroll
            for (int ksd = 0; ksd < 2; ksd++) {
                short8 kb[2];
                #pragma unroll
                for (int nt = 0; nt < 2; nt++)
                    kb[nt] = *(const short8*)&Kp[ksd * 2048
                               + ((half * 2 + nt) * 16 + li) * 32
                               + ((quad ^ gkr) * 8)];
                __builtin_amdgcn_s_setprio(1);
                #pragma unroll
                for (int mt = 0; mt < 2; mt++)
                    #pragma unroll
                    for (int nt = 0; nt < 2; nt++)
                        sa[mt][nt] = __builtin_amdgcn_mfma_f32_16x16x32_bf16(
                            qa[mt][ksd], kb[nt], sa[mt][nt], 0, 0, 0);
                __builtin_amdgcn_s_setprio(0);
            }

            // p = exp2(s [+ log2e]); write P (32 cols)
            bool nomask  = (kt2h + 31 <= qw);      // max key <= min q
            bool allmask = (kt2h > qw + 31);       // min key > max q
            if (nomask || allmask) {
                float MB = allmask ? MC2 : 0.0f;
                #pragma unroll
                for (int mt = 0; mt < 2; mt++)
                    #pragma unroll
                    for (int nt = 0; nt < 2; nt++) {
                        f32x4 s = sa[mt][nt];
                        #pragma unroll
                        for (int r = 0; r < 4; r++) {
                            float p = __builtin_amdgcn_exp2f(s[r] + MB);
                            Pw[(mt * 16 + quad * 4 + r) * 40 + nt * 16 + li] = f2b(p);
                        }
                    }
            } else {
                #pragma unroll
                for (int mt = 0; mt < 2; mt++) {
                    int qrow = qw + mt * 16 + quad * 4;     // + r below
                    #pragma unroll
                    for (int nt = 0; nt < 2; nt++) {
                        int key = kt2h + nt * 16 + li;
                        f32x4 s = sa[mt][nt];
                        #pragma unroll
                        for (int r = 0; r < 4; r++) {
                            float arg = (key > qrow + r) ? s[r] + MC2 : s[r];
                            float p = __builtin_amdgcn_exp2f(arg);
                            Pw[(mt * 16 + quad * 4 + r) * 40 + nt * 16 + li] = f2b(p);
                        }
                    }
                }
            }

            // O += P V ;  l += P 1 (matrix pipe), keys of this half
            short8 vbf[4], pa[2];
            #pragma unroll
            for (int dt = 0; dt < 4; dt++) {
                int d = dt * 16 + li;
                int sw = ((d >> 3) & 3) << 3;
                vbf[dt] = *(const short8*)&Vp[half * 2048 + d * 32 + ((quad * 8) ^ sw)];
            }
            #pragma unroll
            for (int mt = 0; mt < 2; mt++)
                pa[mt] = *(const short8*)&Pw[(mt * 16 + li) * 40 + quad * 8];
            __builtin_amdgcn_s_setprio(1);
            #pragma unroll
            for (int mt = 0; mt < 2; mt++) {
                lacc[mt] = __builtin_amdgcn_mfma_f32_16x16x32_bf16(
                    pa[mt], ones, lacc[mt], 0, 0, 0);
                #pragma unroll
                for (int dt = 0; dt < 4; dt++)
                    oacc[mt][dt] = __builtin_amdgcn_mfma_f32_16x16x32_bf16(
                        pa[mt], vbf[dt], oacc[mt][dt], 0, 0, 0);
            }
            __builtin_amdgcn_s_setprio(0);
        }

        // one barrier per window: vmcnt(0)+lgkmcnt(0) drain covers the
        // prefetch (which had the whole compute above to complete) and
        // orders the buffer swap (WAR on Kt/Vt[nb] next iteration).
        __syncthreads();
    }

    #pragma unroll
    for (int mt = 0; mt < 2; mt++)
        #pragma unroll
        for (int r = 0; r < 4; r++) {
            float inv = 1.0f / lacc[mt][r];
            long row = rowb + qw + mt * 16 + quad * 4 + r;
            #pragma unroll
            for (int dt = 0; dt < 4; dt++)
                O[row * 512 + hd * 64 + dt * 16 + li] = f2b(oacc[mt][dt][r] * inv);
        }
}

// ---------------------------------------------------------------------------
// LN1: xb + AO (both bf16 plain) -> X1 bf16 plain (u32-vectorized).
// ROUND-5-VERIFIED version (wave-per-row rewrite REGRESSED ~44us, reverted).
// ---------------------------------------------------------------------------
__global__ __launch_bounds__(256) void ln1_kernel(const bf16* __restrict__ xb,
                                                  const bf16* __restrict__ ao,
                                                  const void* __restrict__ g,
                                                  const void* __restrict__ beta,
                                                  bf16* __restrict__ x1,
                                                  const int* __restrict__ flagp)
{
    const int f32 = *flagp;
    long base = (long)blockIdx.x * 512;
    int tid = threadIdx.x;
    int d2 = tid * 2;
    float x0, x1v, a0, a1;
    unpack2(*(const u32*)&xb[base + d2], x0, x1v);
    unpack2(*(const u32*)&ao[base + d2], a0, a1);
    float v0 = x0 + a0, v1 = x1v + a1;
    float s1 = v0 + v1;
    float s2 = v0 * v0 + v1 * v1;
    #pragma unroll
    for (int off = 32; off > 0; off >>= 1) {
        s1 += __shfl_down(s1, off);
        s2 += __shfl_down(s2, off);
    }
    __shared__ float w1[4], w2[4];
    int wid = tid >> 6, lane = tid & 63;
    if (lane == 0) { w1[wid] = s1; w2[wid] = s2; }
    __syncthreads();
    float t1 = w1[0] + w1[1] + w1[2] + w1[3];
    float t2 = w2[0] + w2[1] + w2[2] + w2[3];
    float mu = t1 * (1.0f / DMODEL);
    float var = t2 * (1.0f / DMODEL) - mu * mu;
    float rs = rsqrtf(var + 1e-5f);
    float r0 = (v0 - mu) * rs * ldE(g, d2, f32) + ldE(beta, d2, f32);
    float r1 = (v1 - mu) * rs * ldE(g, d2 + 1, f32) + ldE(beta, d2 + 1, f32);
    *(u32*)&x1[base + d2] = pack2(r0, r1);
}

// ---------------------------------------------------------------------------
// LN2: X1 + FF2 -> d_out (external dtype, (S,B,D) layout).
// ROUND-5-VERIFIED version (wave-per-row rewrite REGRESSED, reverted).
// ---------------------------------------------------------------------------
__global__ __launch_bounds__(256) void ln2_kernel(const bf16* __restrict__ x1,
                                                  const bf16* __restrict__ ff2,
                                                  const void* __restrict__ g,
                                                  const void* __restrict__ beta,
                                                  void* __restrict__ outp,
                                                  const int* __restrict__ flagp)
{
    const int f32 = *flagp;
    int m = blockIdx.x;                 // b*SEQ + s
    int b = m >> 11, s = m & 2047;
    long plain = (long)m * 512;
    long funny = ((long)s * BATCH + b) * 512;
    int tid = threadIdx.x;
    int d2 = tid * 2;
    float x0, x1v, a0, a1;
    unpack2(*(const u32*)&x1[plain + d2], x0, x1v);
    unpack2(*(const u32*)&ff2[plain + d2], a0, a1);
    float v0 = x0 + a0, v1 = x1v + a1;
    float s1 = v0 + v1;
    float s2 = v0 * v0 + v1 * v1;
    #pragma unroll
    for (int off = 32; off > 0; off >>= 1) {
        s1 += __shfl_down(s1, off);
        s2 += __shfl_down(s2, off);
    }
    __shared__ float w1[4], w2[4];
    int wid = tid >> 6, lane = tid & 63;
    if (lane == 0) { w1[wid] = s1; w2[wid] = s2; }
    __syncthreads();
    float t1 = w1[0] + w1[1] + w1[2] + w1[3];
    float t2 = w2[0] + w2[1] + w2[2] + w2[3];
    float mu = t1 * (1.0f / DMODEL);
    float var = t2 * (1.0f / DMODEL) - mu * mu;
    float rs = rsqrtf(var + 1e-5f);
    float r0 = (v0 - mu) * rs * ldE(g, d2, f32) + ldE(beta, d2, f32);
    float r1 = (v1 - mu) * rs * ldE(g, d2 + 1, f32) + ldE(beta, d2 + 1, f32);
    if (f32) {
        ((float*)outp)[funny + d2]     = r0;
        ((float*)outp)[funny + d2 + 1] = r1;
    } else {
        *(u32*)&((bf16*)outp)[funny + d2] = pack2(r0, r1);
    }
}

// ---------------------------------------------------------------------------
extern "C" void kernel_launch(void* const* d_in, const int* in_sizes, int n_in,
                              void* d_out, int out_size, void* d_ws, size_t ws_size,
                              hipStream_t stream)
{
    (void)in_sizes; (void)n_in; (void)out_size; (void)ws_size;
    const void* x = d_in[0];

    // bf16 workspace layout (elements):
    bf16* W    = (bf16*)d_ws;
    bf16* xb   = W;                       // [0, 8M)   dead after LN1
    bf16* QVR  = W + (8u  << 20);         // [8M, 32M) Q|V|R cols; H written into V slots
    bf16* Ob   = W + (32u << 20);         // [32M,40M) dead after Wo gemm
    bf16* VTg  = W + (40u << 20);         // [40M,48M) V^T swizzled, dead after attn
    bf16* AO   = W + (40u << 20);         // same region, written after attn
    bf16* X1   = W + (8u  << 20);         // reuse QVR head, alive until LN2
    bf16* FFH  = W + (16u << 20);         // [16M,48M) after LN1
    bf16* FF2  = W;                       // reuse xb
    int*  flag = (int*)((char*)d_ws + (size_t)96 * 1024 * 1024);
    bf16* Wt   = (bf16*)((char*)d_ws + (size_t)96 * 1024 * 1024 + 16);
    bf16* Wqvr = Wt;                      // [1536][512]
    bf16* Wob  = Wt + 786432;             // [512][512]
    bf16* Wf1t = Wt + 1048576;            // [2048][512]
    bf16* Wf2t = Wt + 2097152;            // [512][2048]
    bf16* bqvr = Wt + 3145728;
    bf16* bob  = Wt + 3147264;
    bf16* bf1b = Wt + 3147776;
    bf16* bf2b = Wt + 3149824;

    dim3 blk(256);
    probe_kernel<<<1, blk, 0, stream>>>(x, flag);
    prep_all<<<16402, blk, 0, stream>>>(
        x, xb,
        d_in[1], d_in[3], d_in[5], d_in[8], d_in[12], d_in[14],
        d_in[2], d_in[4], d_in[6], d_in[9], d_in[13], d_in[15],
        Wqvr, Wob, Wf1t, Wf2t, bqvr, bob, bf1b, bf2b, flag);

    // combined Q|V|R projection: all 1536 output columns in one dispatch
    mfma_gemm<false><<<dim3(128, 12), blk, 0, stream>>>(
        xb, Wqvr, bqvr, QVR, 512, 512, 1536);

    // V^T precompute (swizzled) into VTg — consumes V slots before recur
    vt_kernel<<<dim3(32, 64), blk, 0, stream>>>(QVR, VTg);

    // chunk-parallel recurrence: R (cols 1024..1535) -> H (cols 512..1023)
    recur_par<<<256, blk, 0, stream>>>(QVR, d_in[7], flag);

    // attention: 512-thread blocks, 256 q-rows each, 64-key prefetched
    // windows, XCD-aware block remap, setprio'd MFMA clusters
    attn_mfma<<<dim3(8, 64), dim3(512), 0, stream>>>(QVR, VTg, Ob);

    // Wo projection (grid-limited 512 blocks -> prefetched 64KB-LDS variant)
    mfma_gemm_pf<false><<<dim3(128, 4), blk, 0, stream>>>(Ob, Wob, bob, AO, 512, 512, 512);

    // LN1
    ln1_kernel<<<MROWS, blk, 0, stream>>>(xb, AO, d_in[10], d_in[11], X1, flag);

    // FF1 (relu)
    mfma_gemm<true><<<dim3(128, 16), blk, 0, stream>>>(X1, Wf1t, bf1b, FFH, 512, 512, 2048);

    // FF2 (grid-limited 512 blocks -> prefetched 64KB-LDS variant)
    mfma_gemm_pf<false><<<dim3(128, 4), blk, 0, stream>>>(FFH, Wf2t, bf2b, FF2, 2048, 2048, 512);

    // LN2 -> d_out
    ln2_kernel<<<MROWS, blk, 0, stream>>>(X1, FF2, d_in[16], d_in[17], d_out, flag);
}